// Round 1
// baseline (663.987 us; speedup 1.0000x reference)
//
#include <hip/hip_runtime.h>
#include <math.h>

// Problem dims
#define B_   48
#define W_   88
#define C_   256
#define H_   32
#define F_   1024
#define BW_  (B_ * W_)        // 4224
#define BWH_ (B_ * W_ * H_)   // 135168

typedef float  f32x4  __attribute__((ext_vector_type(4)));
typedef __bf16 bf16x8 __attribute__((ext_vector_type(8)));

__device__ __forceinline__ unsigned short f2bf(float f) {
  union { float f; unsigned int u; } v; v.f = f;
  unsigned int r = v.u + 0x7FFFu + ((v.u >> 16) & 1u);  // RNE
  return (unsigned short)(r >> 16);
}
__device__ __forceinline__ float bf2f(unsigned short h) {
  union { unsigned int u; float f; } v; v.u = ((unsigned int)h) << 16;
  return v.f;
}

// ---------------------------------------------------------------------------
// Weight transpose: src f32 [in,out] -> dst bf16 [out,in]
// ---------------------------------------------------------------------------
__global__ __launch_bounds__(256) void wt_kernel(const float* __restrict__ src,
                                                 unsigned short* __restrict__ dst,
                                                 int in_dim, int out_dim) {
  int idx = blockIdx.x * 256 + threadIdx.x;
  if (idx >= in_dim * out_dim) return;
  int i = idx % in_dim;
  int o = idx / in_dim;
  dst[idx] = f2bf(src[(size_t)i * out_dim + o]);  // coalesced write, strided read
}

// ---------------------------------------------------------------------------
// features [B,C,H,W] -> kn = LN(kv+cross_pe)*g+b, vn = LN(kv)*g+b
// out layout [B,W,H,C] flattened = [BWH_, C_] bf16 (GEMM A operand)
// one block handles (b, h, 8 w's)
// ---------------------------------------------------------------------------
__global__ __launch_bounds__(256) void ln_transpose(
    const float* __restrict__ features, const float* __restrict__ cross_pe,
    const float* __restrict__ g_kv, const float* __restrict__ b_kv,
    const float* __restrict__ g_vc, const float* __restrict__ b_vc,
    unsigned short* __restrict__ kn, unsigned short* __restrict__ vn) {
  int blk = blockIdx.x;
  int wt = blk % 11;
  int h  = (blk / 11) % H_;
  int b  = blk / (11 * H_);
  __shared__ float tile[8][C_ + 1];
  __shared__ float st[8][4];  // mu_v, rs_v, mu_k, rs_k
  int tid = threadIdx.x;
  int wl  = tid & 7;
  int w   = wt * 8 + wl;
#pragma unroll
  for (int it = 0; it < 8; it++) {
    int c = (tid >> 3) + (it << 5);
    tile[wl][c] = features[(((size_t)b * C_ + c) * H_ + h) * W_ + w];
  }
  __syncthreads();
  int gw = tid >> 5, gl = tid & 31;  // 32 threads per w
  float s1 = 0, s2 = 0, p1 = 0, p2 = 0;
  for (int c = gl; c < C_; c += 32) {
    float v  = tile[gw][c];
    float vp = v + cross_pe[h * C_ + c];
    s1 += v;  s2 += v * v;
    p1 += vp; p2 += vp * vp;
  }
#pragma unroll
  for (int m = 16; m > 0; m >>= 1) {
    s1 += __shfl_xor(s1, m, 32);
    s2 += __shfl_xor(s2, m, 32);
    p1 += __shfl_xor(p1, m, 32);
    p2 += __shfl_xor(p2, m, 32);
  }
  if (gl == 0) {
    float mu_v = s1 * (1.f / C_);
    float rs_v = rsqrtf(s2 * (1.f / C_) - mu_v * mu_v + 1e-5f);
    float mu_k = p1 * (1.f / C_);
    float rs_k = rsqrtf(p2 * (1.f / C_) - mu_k * mu_k + 1e-5f);
    st[gw][0] = mu_v; st[gw][1] = rs_v; st[gw][2] = mu_k; st[gw][3] = rs_k;
  }
  __syncthreads();
  for (int wv = 0; wv < 8; wv++) {
    int c = tid;
    float v  = tile[wv][c];
    float vp = v + cross_pe[h * C_ + c];
    size_t row = ((size_t)b * W_ + (wt * 8 + wv)) * H_ + h;
    vn[row * C_ + c] = f2bf((v  - st[wv][0]) * st[wv][1] * g_vc[c] + b_vc[c]);
    kn[row * C_ + c] = f2bf((vp - st[wv][2]) * st[wv][3] * g_kv[c] + b_kv[c]);
  }
}

// ---------------------------------------------------------------------------
// Row LayerNorm: x f32 [rows, C_] (+ optional pe[row % pe_mod]) -> bf16 out
// ---------------------------------------------------------------------------
__global__ __launch_bounds__(256) void ln_rows(
    const float* __restrict__ x, const float* __restrict__ pe, int pe_mod,
    const float* __restrict__ g, const float* __restrict__ bta,
    unsigned short* __restrict__ out) {
  int row = blockIdx.x, c = threadIdx.x;
  float v = x[(size_t)row * C_ + c];
  if (pe) v += pe[(size_t)(row % pe_mod) * C_ + c];
  float s1 = v, s2 = v * v;
#pragma unroll
  for (int m = 32; m > 0; m >>= 1) {
    s1 += __shfl_xor(s1, m, 64);
    s2 += __shfl_xor(s2, m, 64);
  }
  __shared__ float red[8];
  int wave = c >> 6;
  if ((c & 63) == 0) { red[wave] = s1; red[4 + wave] = s2; }
  __syncthreads();
  s1 = red[0] + red[1] + red[2] + red[3];
  s2 = red[4] + red[5] + red[6] + red[7];
  float mu = s1 * (1.f / C_);
  float rs = rsqrtf(s2 * (1.f / C_) - mu * mu + 1e-5f);
  out[(size_t)row * C_ + c] = f2bf((v - mu) * rs * g[c] + bta[c]);
}

// ---------------------------------------------------------------------------
// GEMM: out[M,N] = A[M,K](bf16) @ Bt[N,K](bf16)^T, fp32 acc.
// Epilogue: +bias[N], optional exact-GELU, +resid[M,N], write f32 or bf16.
// 64x64 tile, 4 waves of 32x32, mfma_f32_16x16x32_bf16. M,N %64==0, K%32==0.
// ---------------------------------------------------------------------------
__global__ __launch_bounds__(256) void gemm_bt(
    const unsigned short* __restrict__ A, const unsigned short* __restrict__ Bt,
    int M, int N, int K,
    const float* __restrict__ bias, const float* __restrict__ resid,
    float* __restrict__ outF, unsigned short* __restrict__ outB, int act_gelu) {
  __shared__ __attribute__((aligned(16))) unsigned short As[64][32];
  __shared__ __attribute__((aligned(16))) unsigned short Bs[64][32];
  const int tiles_n = N >> 6;
  const int bm = blockIdx.x / tiles_n;
  const int bn = blockIdx.x % tiles_n;
  const int tid = threadIdx.x;
  const int wave = tid >> 6, lane = tid & 63;
  const int quad = lane >> 4, lr = lane & 15;
  const int wm = (wave >> 1) << 5, wn = (wave & 1) << 5;
  const int lrow = tid >> 2;        // 0..63
  const int lcol = (tid & 3) << 3;  // 0,8,16,24
  const size_t a_base = (size_t)(bm * 64 + lrow) * K + lcol;
  const size_t b_base = (size_t)(bn * 64 + lrow) * K + lcol;
  f32x4 acc[2][2] = {};
  for (int k0 = 0; k0 < K; k0 += 32) {
    *(uint4*)&As[lrow][lcol] = *(const uint4*)(A + a_base + k0);
    *(uint4*)&Bs[lrow][lcol] = *(const uint4*)(Bt + b_base + k0);
    __syncthreads();
    bf16x8 af0 = *(const bf16x8*)&As[wm + lr][quad << 3];
    bf16x8 af1 = *(const bf16x8*)&As[wm + 16 + lr][quad << 3];
    bf16x8 bf0 = *(const bf16x8*)&Bs[wn + lr][quad << 3];
    bf16x8 bf1 = *(const bf16x8*)&Bs[wn + 16 + lr][quad << 3];
    acc[0][0] = __builtin_amdgcn_mfma_f32_16x16x32_bf16(af0, bf0, acc[0][0], 0, 0, 0);
    acc[0][1] = __builtin_amdgcn_mfma_f32_16x16x32_bf16(af0, bf1, acc[0][1], 0, 0, 0);
    acc[1][0] = __builtin_amdgcn_mfma_f32_16x16x32_bf16(af1, bf0, acc[1][0], 0, 0, 0);
    acc[1][1] = __builtin_amdgcn_mfma_f32_16x16x32_bf16(af1, bf1, acc[1][1], 0, 0, 0);
    __syncthreads();
  }
#pragma unroll
  for (int i = 0; i < 2; i++)
#pragma unroll
    for (int j = 0; j < 2; j++)
#pragma unroll
      for (int rr = 0; rr < 4; rr++) {
        int row = bm * 64 + wm + i * 16 + quad * 4 + rr;  // C/D: row = quad*4+reg
        int col = bn * 64 + wn + j * 16 + lr;             //      col = lane&15
        float val = acc[i][j][rr];
        if (bias) val += bias[col];
        if (act_gelu) val = 0.5f * val * (1.f + erff(val * 0.70710678118654752f));
        if (resid) val += resid[(size_t)row * N + col];
        if (outF) outF[(size_t)row * N + col] = val;
        else outB[(size_t)row * N + col] = f2bf(val);
      }
}

// ---------------------------------------------------------------------------
// Cross attention: per (b,w) block. q f32 [BW_,C_]; k,v bf16 [BWH_,C_].
// 8 heads x 32 dim; 32 key positions. out bf16 [BW_,C_] (pre-projection).
// ---------------------------------------------------------------------------
__global__ __launch_bounds__(256) void cross_attn(
    const float* __restrict__ qc, const unsigned short* __restrict__ kk,
    const unsigned short* __restrict__ vv, unsigned short* __restrict__ out) {
  int bw = blockIdx.x;
  int tid = threadIdx.x;
  int head = tid >> 5, l = tid & 31;
  __shared__ float qs[C_];
  __shared__ float ps[C_];
  qs[tid] = qc[(size_t)bw * C_ + tid];
  __syncthreads();
  // lane l = key position j
  const unsigned short* kr = kk + ((size_t)bw * H_ + l) * C_ + head * 32;
  float s = 0;
#pragma unroll
  for (int d = 0; d < 32; d++) s += qs[head * 32 + d] * bf2f(kr[d]);
  s *= 0.17677669529663689f;  // 1/sqrt(32)
  float mx = s;
#pragma unroll
  for (int m = 16; m > 0; m >>= 1) mx = fmaxf(mx, __shfl_xor(mx, m, 32));
  float e = __expf(s - mx);
  float sum = e;
#pragma unroll
  for (int m = 16; m > 0; m >>= 1) sum += __shfl_xor(sum, m, 32);
  ps[tid] = e / sum;
  __syncthreads();
  // lane l = output dim d
  float o = 0;
#pragma unroll 8
  for (int j = 0; j < H_; j++) {
    float p = ps[head * 32 + j];
    o += p * bf2f(vv[((size_t)bw * H_ + j) * C_ + head * 32 + l]);
  }
  out[(size_t)bw * C_ + tid] = f2bf(o);
}

// ---------------------------------------------------------------------------
// Self attention: per (b,head) block; 88 query rows over 88 keys, d=32.
// q,k,v f32 [BW_,C_]; out bf16 [BW_,C_] (pre-projection).
// ---------------------------------------------------------------------------
__global__ __launch_bounds__(128) void self_attn(
    const float* __restrict__ q, const float* __restrict__ k,
    const float* __restrict__ v, unsigned short* __restrict__ out) {
  int b = blockIdx.x >> 3;
  int h = blockIdx.x & 7;
  int r = threadIdx.x;
  __shared__ float sc[W_][W_ + 1];
  if (r >= W_) return;
  size_t base = (size_t)b * W_ * C_ + h * 32;
  float qr[32];
#pragma unroll
  for (int d = 0; d < 32; d++) qr[d] = q[base + (size_t)r * C_ + d];
  for (int m = 0; m < W_; m++) {
    const float* krow = k + base + (size_t)m * C_;
    float s = 0;
#pragma unroll
    for (int d = 0; d < 32; d++) s += qr[d] * krow[d];
    sc[r][m] = s * 0.17677669529663689f;  // 1/sqrt(32)
  }
  float mx = -1e30f;
  for (int m = 0; m < W_; m++) mx = fmaxf(mx, sc[r][m]);
  float sum = 0;
  for (int m = 0; m < W_; m++) { float e = __expf(sc[r][m] - mx); sc[r][m] = e; sum += e; }
  float inv = 1.f / sum;
  float o[32];
#pragma unroll
  for (int d = 0; d < 32; d++) o[d] = 0.f;
  for (int m = 0; m < W_; m++) {
    float p = sc[r][m] * inv;
    const float* vrow = v + base + (size_t)m * C_;
#pragma unroll
    for (int d = 0; d < 32; d++) o[d] += p * vrow[d];
  }
#pragma unroll
  for (int d = 0; d < 32; d++) out[base + (size_t)r * C_ + d] = f2bf(o[d]);
}

// ---------------------------------------------------------------------------
extern "C" void kernel_launch(void* const* d_in, const int* in_sizes, int n_in,
                              void* d_out, int out_size, void* d_ws, size_t ws_size,
                              hipStream_t stream) {
  (void)in_sizes; (void)n_in; (void)out_size; (void)ws_size;
  const float* pooled   = (const float*)d_in[0];
  const float* features = (const float*)d_in[1];
  const float* self_pe  = (const float*)d_in[2];
  const float* cross_pe = (const float*)d_in[3];
  const float* ln_qs_g = (const float*)d_in[4],  *ln_qs_b = (const float*)d_in[5];
  const float* ln_vs_g = (const float*)d_in[6],  *ln_vs_b = (const float*)d_in[7];
  const float* ln_qc_g = (const float*)d_in[8],  *ln_qc_b = (const float*)d_in[9];
  const float* ln_kv_g = (const float*)d_in[10], *ln_kv_b = (const float*)d_in[11];
  const float* ln_vc_g = (const float*)d_in[12], *ln_vc_b = (const float*)d_in[13];
  const float* ln_ffn_g = (const float*)d_in[14], *ln_ffn_b = (const float*)d_in[15];
  const float* Wq_s = (const float*)d_in[16], *Wk_s = (const float*)d_in[17];
  const float* Wv_s = (const float*)d_in[18], *Wp_s = (const float*)d_in[19];
  const float* Wq_c = (const float*)d_in[20], *Wk_c = (const float*)d_in[21];
  const float* Wv_c = (const float*)d_in[22], *Wp_c = (const float*)d_in[23];
  const float* bq_s = (const float*)d_in[24], *bv_s = (const float*)d_in[25];
  const float* bp_s = (const float*)d_in[26], *bq_c = (const float*)d_in[27];
  const float* bv_c = (const float*)d_in[28], *bp_c = (const float*)d_in[29];
  const float* W1 = (const float*)d_in[30], *b1 = (const float*)d_in[31];
  const float* W2 = (const float*)d_in[32], *b2 = (const float*)d_in[33];
  float* outp = (float*)d_out;
  char* ws = (char*)d_ws;

  // ---- workspace layout ----
  size_t off = 0;
  auto alloc = [&](size_t bytes) { size_t o = off; off = (off + bytes + 255) & ~(size_t)255; return o; };
  const size_t big = (size_t)BWH_ * C_ * 2;  // 69.2 MB
  size_t BIGA = alloc(big);   // kn, later v, later phase-B overlay
  size_t BIGB = alloc(big);   // vn
  size_t BIGC = alloc(big);   // k
  // persistent smalls (live alongside big buffers)
  size_t WQS = alloc(65536 * 2), WKS = alloc(65536 * 2), WVS = alloc(65536 * 2), WPS = alloc(65536 * 2);
  size_t WQC = alloc(65536 * 2), WKC = alloc(65536 * 2), WVC = alloc(65536 * 2), WPC = alloc(65536 * 2);
  size_t W1T = alloc(262144 * 2), W2T = alloc(262144 * 2);
  size_t QN_C  = alloc((size_t)BW_ * C_ * 2);
  size_t Q_C   = alloc((size_t)BW_ * C_ * 4);
  size_t ATT_O = alloc((size_t)BW_ * C_ * 2);
  // phase-B buffers overlay the (dead by then) BIGA/BIGB region
  size_t offp = 0;
  auto allocP = [&](size_t bytes) { size_t o = offp; offp = (offp + bytes + 255) & ~(size_t)255; return o; };
  size_t X1   = allocP((size_t)BW_ * C_ * 4);
  size_t QN_S = allocP((size_t)BW_ * C_ * 2);
  size_t VN_S = allocP((size_t)BW_ * C_ * 2);
  size_t Q_S  = allocP((size_t)BW_ * C_ * 4);
  size_t K_S  = allocP((size_t)BW_ * C_ * 4);
  size_t V_S  = allocP((size_t)BW_ * C_ * 4);
  size_t S_O  = allocP((size_t)BW_ * C_ * 2);
  size_t X2   = allocP((size_t)BW_ * C_ * 4);
  size_t FFN  = allocP((size_t)BW_ * C_ * 2);
  size_t H1   = allocP((size_t)BW_ * F_ * 2);

  unsigned short* kn   = (unsigned short*)(ws + BIGA);
  unsigned short* vn   = (unsigned short*)(ws + BIGB);
  unsigned short* kmat = (unsigned short*)(ws + BIGC);
  unsigned short* vmat = (unsigned short*)(ws + BIGA);  // reuse: kn dead after k GEMM
  unsigned short* wqs = (unsigned short*)(ws + WQS), *wks = (unsigned short*)(ws + WKS);
  unsigned short* wvs = (unsigned short*)(ws + WVS), *wps = (unsigned short*)(ws + WPS);
  unsigned short* wqc = (unsigned short*)(ws + WQC), *wkc = (unsigned short*)(ws + WKC);
  unsigned short* wvc = (unsigned short*)(ws + WVC), *wpc = (unsigned short*)(ws + WPC);
  unsigned short* w1t = (unsigned short*)(ws + W1T), *w2t = (unsigned short*)(ws + W2T);
  unsigned short* qn_c  = (unsigned short*)(ws + QN_C);
  float*          q_c   = (float*)(ws + Q_C);
  unsigned short* att_o = (unsigned short*)(ws + ATT_O);
  float*          x1    = (float*)(ws + X1);
  unsigned short* qn_s  = (unsigned short*)(ws + QN_S);
  unsigned short* vn_s  = (unsigned short*)(ws + VN_S);
  float* q_s = (float*)(ws + Q_S), *k_s = (float*)(ws + K_S), *v_s = (float*)(ws + V_S);
  unsigned short* s_o   = (unsigned short*)(ws + S_O);
  float*          x2    = (float*)(ws + X2);
  unsigned short* ffn_n = (unsigned short*)(ws + FFN);
  unsigned short* h1    = (unsigned short*)(ws + H1);

  // 1. weight transposes -> bf16 [out][in]
  wt_kernel<<<256, 256, 0, stream>>>(Wq_s, wqs, 256, 256);
  wt_kernel<<<256, 256, 0, stream>>>(Wk_s, wks, 256, 256);
  wt_kernel<<<256, 256, 0, stream>>>(Wv_s, wvs, 256, 256);
  wt_kernel<<<256, 256, 0, stream>>>(Wp_s, wps, 256, 256);
  wt_kernel<<<256, 256, 0, stream>>>(Wq_c, wqc, 256, 256);
  wt_kernel<<<256, 256, 0, stream>>>(Wk_c, wkc, 256, 256);
  wt_kernel<<<256, 256, 0, stream>>>(Wv_c, wvc, 256, 256);
  wt_kernel<<<256, 256, 0, stream>>>(Wp_c, wpc, 256, 256);
  wt_kernel<<<1024, 256, 0, stream>>>(W1, w1t, 256, 1024);
  wt_kernel<<<1024, 256, 0, stream>>>(W2, w2t, 1024, 256);

  // 2. features -> kn, vn (fused transpose + PE + two LayerNorms)
  ln_transpose<<<B_ * H_ * 11, 256, 0, stream>>>(features, cross_pe,
      ln_kv_g, ln_kv_b, ln_vc_g, ln_vc_b, kn, vn);

  // 3-4. qn_c = LN(pooled); q_c = qn_c @ Wq_c + bq_c  (f32)
  ln_rows<<<BW_, 256, 0, stream>>>(pooled, nullptr, 1, ln_qc_g, ln_qc_b, qn_c);
  gemm_bt<<<(BW_ / 64) * (C_ / 64), 256, 0, stream>>>(qn_c, wqc, BW_, C_, C_,
      bq_c, nullptr, q_c, nullptr, 0);

  // 5-6. k = kn @ Wk_c ; v = vn @ Wv_c + bv_c  (bf16, big GEMMs)
  gemm_bt<<<(BWH_ / 64) * (C_ / 64), 256, 0, stream>>>(kn, wkc, BWH_, C_, C_,
      nullptr, nullptr, nullptr, kmat, 0);
  gemm_bt<<<(BWH_ / 64) * (C_ / 64), 256, 0, stream>>>(vn, wvc, BWH_, C_, C_,
      bv_c, nullptr, nullptr, vmat, 0);

  // 7. cross attention core
  cross_attn<<<BW_, 256, 0, stream>>>(q_c, kmat, vmat, att_o);

  // 8. x1 = att_o @ Wp_c + bp_c + pooled (f32)
  gemm_bt<<<(BW_ / 64) * (C_ / 64), 256, 0, stream>>>(att_o, wpc, BW_, C_, C_,
      bp_c, pooled, x1, nullptr, 0);

  // 9-10. qn_s = LN(x1 + self_pe); vn_s = LN(x1)
  ln_rows<<<BW_, 256, 0, stream>>>(x1, self_pe, W_, ln_qs_g, ln_qs_b, qn_s);
  ln_rows<<<BW_, 256, 0, stream>>>(x1, nullptr, 1, ln_vs_g, ln_vs_b, vn_s);

  // 11-13. q_s, k_s, v_s projections (f32 out)
  gemm_bt<<<(BW_ / 64) * (C_ / 64), 256, 0, stream>>>(qn_s, wqs, BW_, C_, C_,
      bq_s, nullptr, q_s, nullptr, 0);
  gemm_bt<<<(BW_ / 64) * (C_ / 64), 256, 0, stream>>>(qn_s, wks, BW_, C_, C_,
      nullptr, nullptr, k_s, nullptr, 0);
  gemm_bt<<<(BW_ / 64) * (C_ / 64), 256, 0, stream>>>(vn_s, wvs, BW_, C_, C_,
      bv_s, nullptr, v_s, nullptr, 0);

  // 14. self attention core
  self_attn<<<B_ * 8, 128, 0, stream>>>(q_s, k_s, v_s, s_o);

  // 15. x2 = s_o @ Wp_s + bp_s + x1
  gemm_bt<<<(BW_ / 64) * (C_ / 64), 256, 0, stream>>>(s_o, wps, BW_, C_, C_,
      bp_s, x1, x2, nullptr, 0);

  // 16-18. FFN: h1 = gelu(LN(x2) @ W1 + b1); out = h1 @ W2 + b2 + x2
  ln_rows<<<BW_, 256, 0, stream>>>(x2, nullptr, 1, ln_ffn_g, ln_ffn_b, ffn_n);
  gemm_bt<<<(BW_ / 64) * (F_ / 64), 256, 0, stream>>>(ffn_n, w1t, BW_, F_, C_,
      b1, nullptr, nullptr, h1, 1);
  gemm_bt<<<(BW_ / 64) * (C_ / 64), 256, 0, stream>>>(h1, w2t, BW_, C_, F_,
      b2, x2, outp, nullptr, 0);
}

// Round 2
// 594.037 us; speedup vs baseline: 1.1178x; 1.1178x over previous
//
#include <hip/hip_runtime.h>
#include <math.h>

// Problem dims
#define B_   48
#define W_   88
#define C_   256
#define H_   32
#define F_   1024
#define BW_  (B_ * W_)        // 4224
#define BWH_ (B_ * W_ * H_)   // 135168
#define HW_  (H_ * W_)        // 2816

typedef float  f32x4  __attribute__((ext_vector_type(4)));
typedef __bf16 bf16x8 __attribute__((ext_vector_type(8)));

__device__ __forceinline__ unsigned short f2bf(float f) {
  union { float f; unsigned int u; } v; v.f = f;
  unsigned int r = v.u + 0x7FFFu + ((v.u >> 16) & 1u);  // RNE
  return (unsigned short)(r >> 16);
}
__device__ __forceinline__ float bf2f(unsigned short h) {
  union { unsigned int u; float f; } v; v.u = ((unsigned int)h) << 16;
  return v.f;
}

// ---------------------------------------------------------------------------
// Weight transpose: src f32 [in,out] -> dst bf16 [out,in]
// ---------------------------------------------------------------------------
__global__ __launch_bounds__(256) void wt_kernel(const float* __restrict__ src,
                                                 unsigned short* __restrict__ dst,
                                                 int in_dim, int out_dim) {
  int idx = blockIdx.x * 256 + threadIdx.x;
  if (idx >= in_dim * out_dim) return;
  int i = idx % in_dim;
  int o = idx / in_dim;
  dst[idx] = f2bf(src[(size_t)i * out_dim + o]);
}

// ---------------------------------------------------------------------------
// Mqk[n=256h+c][d'] = scale * sum_dd Wq[d',32h+dd]*Wk[c,32h+dd]   (bf16)
// bqk[n] = scale * sum_dd bq[32h+dd]*Wk[c,32h+dd]                 (f32)
// ---------------------------------------------------------------------------
__global__ __launch_bounds__(256) void mqk_build(
    const float* __restrict__ Wq, const float* __restrict__ Wk,
    const float* __restrict__ bq,
    unsigned short* __restrict__ Mqk, float* __restrict__ bqk) {
  int n = blockIdx.x;          // 256h + c
  int h = n >> 8, c = n & 255;
  int t = threadIdx.x;         // d'
  __shared__ float wk_s[32];
  if (t < 32) wk_s[t] = Wk[c * 256 + 32 * h + t];
  __syncthreads();
  const float scale = 0.17677669529663689f;  // 1/sqrt(32)
  float acc = 0.f;
#pragma unroll
  for (int dd = 0; dd < 32; dd++) acc += Wq[t * 256 + 32 * h + dd] * wk_s[dd];
  Mqk[(size_t)n * 256 + t] = f2bf(acc * scale);
  if (t == 0) {
    float bb = 0.f;
    for (int dd = 0; dd < 32; dd++) bb += bq[32 * h + dd] * wk_s[dd];
    bqk[n] = bb * scale;
  }
}

// ---------------------------------------------------------------------------
// Mvp[d][k=256h+c] = sum_dd Wv[c,32h+dd]*Wp[32h+dd,d]   (bf16, [256,2048])
// ---------------------------------------------------------------------------
__global__ __launch_bounds__(256) void mvp_build(
    const float* __restrict__ Wv, const float* __restrict__ Wp,
    unsigned short* __restrict__ Mvp) {
  int d = blockIdx.x;
  int t = threadIdx.x;  // = c
  for (int h = 0; h < 8; h++) {
    float acc = 0.f;
#pragma unroll
    for (int dd = 0; dd < 32; dd++)
      acc += Wv[t * 256 + 32 * h + dd] * Wp[(32 * h + dd) * 256 + d];
    Mvp[(size_t)d * 2048 + h * 256 + t] = f2bf(acc);
  }
}

__global__ void bvp_build(const float* __restrict__ bv, const float* __restrict__ Wp,
                          const float* __restrict__ bp, float* __restrict__ bvp) {
  int d = threadIdx.x;
  float acc = bp[d];
  for (int dp = 0; dp < 256; dp++) acc += bv[dp] * Wp[dp * 256 + d];
  bvp[d] = acc;
}

// ---------------------------------------------------------------------------
// ln_transpose2: features [B,C,H,W] -> kn = LN(kv+pe), vn = LN(kv)
// out rows [(b*W+w)*H + h][C] bf16.  Block = (b, 32 contiguous hw positions).
// Fully coalesced 128B-segment reads.
// ---------------------------------------------------------------------------
__global__ __launch_bounds__(256) void ln_transpose2(
    const float* __restrict__ features, const float* __restrict__ cross_pe,
    const float* __restrict__ g_kv, const float* __restrict__ b_kv,
    const float* __restrict__ g_vc, const float* __restrict__ b_vc,
    unsigned short* __restrict__ kn, unsigned short* __restrict__ vn) {
  int b   = blockIdx.x / 88;
  int tl  = blockIdx.x % 88;
  int hw0 = tl * 32;
  __shared__ float tile[32][257];
  __shared__ float st[32][4];
  int tid = threadIdx.x;
  // load: 8 passes of float4, lanes cover 32 consecutive hw per c
  int l4 = (tid & 7) * 4;
  int cc = tid >> 3;  // 0..31
  const float* fb = features + (size_t)b * C_ * HW_ + hw0;
#pragma unroll
  for (int p = 0; p < 8; p++) {
    int c = cc + p * 32;
    float4 v = *(const float4*)(fb + (size_t)c * HW_ + l4);
    tile[l4 + 0][c] = v.x; tile[l4 + 1][c] = v.y;
    tile[l4 + 2][c] = v.z; tile[l4 + 3][c] = v.w;
  }
  __syncthreads();
  // stats: 8 threads per hw-row
  int row = tid >> 3, ln = tid & 7;
  int hr = (hw0 + row) / 88;
  const float* per = cross_pe + hr * 256;
  float s1 = 0, s2 = 0, p1 = 0, p2 = 0;
  for (int c = ln; c < 256; c += 8) {
    float v  = tile[row][c];
    float vp = v + per[c];
    s1 += v;  s2 += v * v;
    p1 += vp; p2 += vp * vp;
  }
#pragma unroll
  for (int m = 1; m < 8; m <<= 1) {
    s1 += __shfl_xor(s1, m, 8); s2 += __shfl_xor(s2, m, 8);
    p1 += __shfl_xor(p1, m, 8); p2 += __shfl_xor(p2, m, 8);
  }
  if (ln == 0) {
    float mu  = s1 * (1.f / 256.f);
    float rs  = rsqrtf(s2 * (1.f / 256.f) - mu * mu + 1e-5f);
    float muk = p1 * (1.f / 256.f);
    float rsk = rsqrtf(p2 * (1.f / 256.f) - muk * muk + 1e-5f);
    st[row][0] = mu; st[row][1] = rs; st[row][2] = muk; st[row][3] = rsk;
  }
  __syncthreads();
  // write: per row, 256 lanes cover all c -> 512B contiguous bf16 stores
  int c = tid;
  float gv = g_vc[c], bv2 = b_vc[c], gk = g_kv[c], bk = b_kv[c];
  for (int r = 0; r < 32; r++) {
    int hh = (hw0 + r) / 88, ww = (hw0 + r) % 88;
    float v  = tile[r][c];
    float vp = v + cross_pe[hh * 256 + c];
    size_t ro = ((size_t)b * 88 + ww) * 32 + hh;
    vn[ro * 256 + c] = f2bf((v  - st[r][0]) * st[r][1] * gv + bv2);
    kn[ro * 256 + c] = f2bf((vp - st[r][2]) * st[r][3] * gk + bk);
  }
}

// ---------------------------------------------------------------------------
// Row LayerNorm: x f32 [rows, C_] (+ optional pe[row % pe_mod]) -> bf16 out
// ---------------------------------------------------------------------------
__global__ __launch_bounds__(256) void ln_rows(
    const float* __restrict__ x, const float* __restrict__ pe, int pe_mod,
    const float* __restrict__ g, const float* __restrict__ bta,
    unsigned short* __restrict__ out) {
  int row = blockIdx.x, c = threadIdx.x;
  float v = x[(size_t)row * C_ + c];
  if (pe) v += pe[(size_t)(row % pe_mod) * C_ + c];
  float s1 = v, s2 = v * v;
#pragma unroll
  for (int m = 32; m > 0; m >>= 1) {
    s1 += __shfl_xor(s1, m, 64);
    s2 += __shfl_xor(s2, m, 64);
  }
  __shared__ float red[8];
  int wave = c >> 6;
  if ((c & 63) == 0) { red[wave] = s1; red[4 + wave] = s2; }
  __syncthreads();
  s1 = red[0] + red[1] + red[2] + red[3];
  s2 = red[4] + red[5] + red[6] + red[7];
  float mu = s1 * (1.f / C_);
  float rs = rsqrtf(s2 * (1.f / C_) - mu * mu + 1e-5f);
  out[(size_t)row * C_ + c] = f2bf((v - mu) * rs * g[c] + bta[c]);
}

// ---------------------------------------------------------------------------
// GEMM: out[M,N] = A[M,K](bf16) @ Bt[N,K](bf16)^T, fp32 acc.
// Epilogue: +bias[N], optional exact-GELU, +resid[M,N], write f32 or bf16.
// ---------------------------------------------------------------------------
__global__ __launch_bounds__(256) void gemm_bt(
    const unsigned short* __restrict__ A, const unsigned short* __restrict__ Bt,
    int M, int N, int K,
    const float* __restrict__ bias, const float* __restrict__ resid,
    float* __restrict__ outF, unsigned short* __restrict__ outB, int act_gelu) {
  __shared__ __attribute__((aligned(16))) unsigned short As[64][32];
  __shared__ __attribute__((aligned(16))) unsigned short Bs[64][32];
  const int tiles_n = N >> 6;
  const int bm = blockIdx.x / tiles_n;
  const int bn = blockIdx.x % tiles_n;
  const int tid = threadIdx.x;
  const int wave = tid >> 6, lane = tid & 63;
  const int quad = lane >> 4, lr = lane & 15;
  const int wm = (wave >> 1) << 5, wn = (wave & 1) << 5;
  const int lrow = tid >> 2;
  const int lcol = (tid & 3) << 3;
  const size_t a_base = (size_t)(bm * 64 + lrow) * K + lcol;
  const size_t b_base = (size_t)(bn * 64 + lrow) * K + lcol;
  f32x4 acc[2][2] = {};
  for (int k0 = 0; k0 < K; k0 += 32) {
    *(uint4*)&As[lrow][lcol] = *(const uint4*)(A + a_base + k0);
    *(uint4*)&Bs[lrow][lcol] = *(const uint4*)(Bt + b_base + k0);
    __syncthreads();
    bf16x8 af0 = *(const bf16x8*)&As[wm + lr][quad << 3];
    bf16x8 af1 = *(const bf16x8*)&As[wm + 16 + lr][quad << 3];
    bf16x8 bf0 = *(const bf16x8*)&Bs[wn + lr][quad << 3];
    bf16x8 bf1 = *(const bf16x8*)&Bs[wn + 16 + lr][quad << 3];
    acc[0][0] = __builtin_amdgcn_mfma_f32_16x16x32_bf16(af0, bf0, acc[0][0], 0, 0, 0);
    acc[0][1] = __builtin_amdgcn_mfma_f32_16x16x32_bf16(af0, bf1, acc[0][1], 0, 0, 0);
    acc[1][0] = __builtin_amdgcn_mfma_f32_16x16x32_bf16(af1, bf0, acc[1][0], 0, 0, 0);
    acc[1][1] = __builtin_amdgcn_mfma_f32_16x16x32_bf16(af1, bf1, acc[1][1], 0, 0, 0);
    __syncthreads();
  }
#pragma unroll
  for (int i = 0; i < 2; i++)
#pragma unroll
    for (int j = 0; j < 2; j++)
#pragma unroll
      for (int rr = 0; rr < 4; rr++) {
        int row = bm * 64 + wm + i * 16 + quad * 4 + rr;
        int col = bn * 64 + wn + j * 16 + lr;
        float val = acc[i][j][rr];
        if (bias) val += bias[col];
        if (act_gelu) val = 0.5f * val * (1.f + erff(val * 0.70710678118654752f));
        if (resid) val += resid[(size_t)row * N + col];
        if (outF) outF[(size_t)row * N + col] = val;
        else outB[(size_t)row * N + col] = f2bf(val);
      }
}

// ---------------------------------------------------------------------------
// cross_attn2: per (b,w). qt [BW_,2048] bf16 (folded q~), kn/vn [BWH_,256] bf16.
// s[h][j] = qt[h-slice] . kn[j]; softmax over j; ctx[h][c] = sum_j p*vn[j][c].
// Writes ctx [BW_, 2048] bf16.
// ---------------------------------------------------------------------------
#define KSTR 264  // padded ushort row stride: 528B, 16B-aligned, conflict-free
__global__ __launch_bounds__(256) void cross_attn2(
    const unsigned short* __restrict__ qt_g,
    const unsigned short* __restrict__ kn, const unsigned short* __restrict__ vn,
    unsigned short* __restrict__ ctx_g) {
  int bw = blockIdx.x;
  int tid = threadIdx.x;
  __shared__ __attribute__((aligned(16))) unsigned short qtl[8][KSTR];
  __shared__ __attribute__((aligned(16))) unsigned short knl[32][KSTR];
  __shared__ __attribute__((aligned(16))) unsigned short vnl[32][KSTR];
  __shared__ float s_sc[32 * 9];
  __shared__ float ps[8 * 36];
  __shared__ __attribute__((aligned(16))) unsigned short ctxl[2048];

  // ---- stage q~ (4KB), kn (16KB), vn (16KB) ----
  {
    uint4 qv = *(const uint4*)(qt_g + (size_t)bw * 2048 + tid * 8);
    int h = tid >> 5, c0 = (tid & 31) * 8;
    *(uint4*)&qtl[h][c0] = qv;
    int j = tid >> 3, cs = (tid & 7) * 32;
    const unsigned short* kr = kn + ((size_t)bw * 32 + j) * 256 + cs;
    const unsigned short* vr = vn + ((size_t)bw * 32 + j) * 256 + cs;
#pragma unroll
    for (int k = 0; k < 4; k++) {
      *(uint4*)&knl[j][cs + k * 8] = *(const uint4*)(kr + k * 8);
      *(uint4*)&vnl[j][cs + k * 8] = *(const uint4*)(vr + k * 8);
    }
  }
  __syncthreads();
  // ---- scores: thread (j = tid>>3, h = tid&7); kn row broadcast over 8 heads
  {
    int j = tid >> 3, h = tid & 7;
    float acc = 0.f;
#pragma unroll
    for (int c8 = 0; c8 < 32; c8++) {
      bf16x8 kk = *(const bf16x8*)&knl[j][c8 * 8];
      bf16x8 qq = *(const bf16x8*)&qtl[h][c8 * 8];
#pragma unroll
      for (int i = 0; i < 8; i++) acc += (float)qq[i] * (float)kk[i];
    }
    s_sc[j * 9 + h] = acc;
  }
  __syncthreads();
  // ---- softmax: thread (h = tid>>5, j = tid&31), reduce within half-wave
  {
    int h = tid >> 5, j = tid & 31;
    float s = s_sc[j * 9 + h];
    float mx = s;
#pragma unroll
    for (int m = 16; m > 0; m >>= 1) mx = fmaxf(mx, __shfl_xor(mx, m, 32));
    float e = __expf(s - mx);
    float sum = e;
#pragma unroll
    for (int m = 16; m > 0; m >>= 1) sum += __shfl_xor(sum, m, 32);
    ps[h * 36 + j] = e / sum;
  }
  __syncthreads();
  // ---- ctx: thread (h = tid&7, c0 = (tid>>3)*8); vn row broadcast over 8 heads
  {
    int h = tid & 7, c0 = (tid >> 3) * 8;
    float acc[8];
#pragma unroll
    for (int i = 0; i < 8; i++) acc[i] = 0.f;
#pragma unroll 8
    for (int j = 0; j < 32; j++) {
      float p = ps[h * 36 + j];
      bf16x8 vv = *(const bf16x8*)&vnl[j][c0];
#pragma unroll
      for (int i = 0; i < 8; i++) acc[i] += p * (float)vv[i];
    }
    unsigned short pk[8];
#pragma unroll
    for (int i = 0; i < 8; i++) pk[i] = f2bf(acc[i]);
    *(uint4*)&ctxl[h * 256 + c0] = *(uint4*)pk;
  }
  __syncthreads();
  *(uint4*)(ctx_g + (size_t)bw * 2048 + tid * 8) = *(const uint4*)&ctxl[tid * 8];
}

// ---------------------------------------------------------------------------
// Self attention: per (b,head); 88 queries x 88 keys, d=32.
// ---------------------------------------------------------------------------
__global__ __launch_bounds__(128) void self_attn(
    const float* __restrict__ q, const float* __restrict__ k,
    const float* __restrict__ v, unsigned short* __restrict__ out) {
  int b = blockIdx.x >> 3;
  int h = blockIdx.x & 7;
  int r = threadIdx.x;
  __shared__ float sc[W_][W_ + 1];
  if (r >= W_) return;
  size_t base = (size_t)b * W_ * C_ + h * 32;
  float qr[32];
#pragma unroll
  for (int d = 0; d < 32; d++) qr[d] = q[base + (size_t)r * C_ + d];
  for (int m = 0; m < W_; m++) {
    const float* krow = k + base + (size_t)m * C_;
    float s = 0;
#pragma unroll
    for (int d = 0; d < 32; d++) s += qr[d] * krow[d];
    sc[r][m] = s * 0.17677669529663689f;
  }
  float mx = -1e30f;
  for (int m = 0; m < W_; m++) mx = fmaxf(mx, sc[r][m]);
  float sum = 0;
  for (int m = 0; m < W_; m++) { float e = __expf(sc[r][m] - mx); sc[r][m] = e; sum += e; }
  float inv = 1.f / sum;
  float o[32];
#pragma unroll
  for (int d = 0; d < 32; d++) o[d] = 0.f;
  for (int m = 0; m < W_; m++) {
    float p = sc[r][m] * inv;
    const float* vrow = v + base + (size_t)m * C_;
#pragma unroll
    for (int d = 0; d < 32; d++) o[d] += p * vrow[d];
  }
#pragma unroll
  for (int d = 0; d < 32; d++) out[base + (size_t)r * C_ + d] = f2bf(o[d]);
}

// ---------------------------------------------------------------------------
extern "C" void kernel_launch(void* const* d_in, const int* in_sizes, int n_in,
                              void* d_out, int out_size, void* d_ws, size_t ws_size,
                              hipStream_t stream) {
  (void)in_sizes; (void)n_in; (void)out_size; (void)ws_size;
  const float* pooled   = (const float*)d_in[0];
  const float* features = (const float*)d_in[1];
  const float* self_pe  = (const float*)d_in[2];
  const float* cross_pe = (const float*)d_in[3];
  const float* ln_qs_g = (const float*)d_in[4],  *ln_qs_b = (const float*)d_in[5];
  const float* ln_vs_g = (const float*)d_in[6],  *ln_vs_b = (const float*)d_in[7];
  const float* ln_qc_g = (const float*)d_in[8],  *ln_qc_b = (const float*)d_in[9];
  const float* ln_kv_g = (const float*)d_in[10], *ln_kv_b = (const float*)d_in[11];
  const float* ln_vc_g = (const float*)d_in[12], *ln_vc_b = (const float*)d_in[13];
  const float* ln_ffn_g = (const float*)d_in[14], *ln_ffn_b = (const float*)d_in[15];
  const float* Wq_s = (const float*)d_in[16], *Wk_s = (const float*)d_in[17];
  const float* Wv_s = (const float*)d_in[18], *Wp_s = (const float*)d_in[19];
  const float* Wq_c = (const float*)d_in[20], *Wk_c = (const float*)d_in[21];
  const float* Wv_c = (const float*)d_in[22], *Wp_c = (const float*)d_in[23];
  const float* bq_s = (const float*)d_in[24], *bv_s = (const float*)d_in[25];
  const float* bp_s = (const float*)d_in[26], *bq_c = (const float*)d_in[27];
  const float* bv_c = (const float*)d_in[28], *bp_c = (const float*)d_in[29];
  const float* W1 = (const float*)d_in[30], *b1 = (const float*)d_in[31];
  const float* W2 = (const float*)d_in[32], *b2 = (const float*)d_in[33];
  float* outp = (float*)d_out;
  char* ws = (char*)d_ws;

  // ---- workspace layout ----
  size_t off = 0;
  auto alloc = [&](size_t bytes) { size_t o = off; off = (off + bytes + 255) & ~(size_t)255; return o; };
  const size_t big = (size_t)BWH_ * C_ * 2;          // 69.2 MB each
  size_t KN  = alloc(big);
  size_t VN  = alloc(big);
  size_t QT  = alloc((size_t)BW_ * 2048 * 2);        // 17.3 MB
  size_t CTX = alloc((size_t)BW_ * 2048 * 2);        // 17.3 MB
  size_t MQK = alloc((size_t)2048 * 256 * 2);
  size_t MVP = alloc((size_t)256 * 2048 * 2);
  size_t BQK = alloc(2048 * 4);
  size_t BVP = alloc(256 * 4);
  size_t WQS = alloc(65536 * 2), WKS = alloc(65536 * 2);
  size_t WVS = alloc(65536 * 2), WPS = alloc(65536 * 2);
  size_t W1T = alloc(262144 * 2), W2T = alloc(262144 * 2);
  size_t QN_C = alloc((size_t)BW_ * C_ * 2);
  // phase-B overlays the KN/VN region (dead after cross_attn2)
  size_t offp = KN;
  auto allocP = [&](size_t bytes) { size_t o = offp; offp = (offp + bytes + 255) & ~(size_t)255; return o; };
  size_t X1   = allocP((size_t)BW_ * C_ * 4);
  size_t QN_S = allocP((size_t)BW_ * C_ * 2);
  size_t VN_S = allocP((size_t)BW_ * C_ * 2);
  size_t Q_S  = allocP((size_t)BW_ * C_ * 4);
  size_t K_S  = allocP((size_t)BW_ * C_ * 4);
  size_t V_S  = allocP((size_t)BW_ * C_ * 4);
  size_t S_O  = allocP((size_t)BW_ * C_ * 2);
  size_t X2   = allocP((size_t)BW_ * C_ * 4);
  size_t FFN  = allocP((size_t)BW_ * C_ * 2);
  size_t H1   = allocP((size_t)BW_ * F_ * 2);

  unsigned short* kn   = (unsigned short*)(ws + KN);
  unsigned short* vn   = (unsigned short*)(ws + VN);
  unsigned short* qt   = (unsigned short*)(ws + QT);
  unsigned short* ctx  = (unsigned short*)(ws + CTX);
  unsigned short* mqk  = (unsigned short*)(ws + MQK);
  unsigned short* mvp  = (unsigned short*)(ws + MVP);
  float* bqk = (float*)(ws + BQK);
  float* bvp = (float*)(ws + BVP);
  unsigned short* wqs = (unsigned short*)(ws + WQS), *wks = (unsigned short*)(ws + WKS);
  unsigned short* wvs = (unsigned short*)(ws + WVS), *wps = (unsigned short*)(ws + WPS);
  unsigned short* w1t = (unsigned short*)(ws + W1T), *w2t = (unsigned short*)(ws + W2T);
  unsigned short* qn_c = (unsigned short*)(ws + QN_C);
  float*          x1   = (float*)(ws + X1);
  unsigned short* qn_s = (unsigned short*)(ws + QN_S);
  unsigned short* vn_s = (unsigned short*)(ws + VN_S);
  float* q_s = (float*)(ws + Q_S), *k_s = (float*)(ws + K_S), *v_s = (float*)(ws + V_S);
  unsigned short* s_o  = (unsigned short*)(ws + S_O);
  float*          x2   = (float*)(ws + X2);
  unsigned short* ffn_n = (unsigned short*)(ws + FFN);
  unsigned short* h1    = (unsigned short*)(ws + H1);

  // 1. transposed bf16 weights (self + FFN only; cross weights are folded)
  wt_kernel<<<256, 256, 0, stream>>>(Wq_s, wqs, 256, 256);
  wt_kernel<<<256, 256, 0, stream>>>(Wk_s, wks, 256, 256);
  wt_kernel<<<256, 256, 0, stream>>>(Wv_s, wvs, 256, 256);
  wt_kernel<<<256, 256, 0, stream>>>(Wp_s, wps, 256, 256);
  wt_kernel<<<1024, 256, 0, stream>>>(W1, w1t, 256, 1024);
  wt_kernel<<<1024, 256, 0, stream>>>(W2, w2t, 1024, 256);

  // 2. folded cross-attention matrices
  mqk_build<<<2048, 256, 0, stream>>>(Wq_c, Wk_c, bq_c, mqk, bqk);
  mvp_build<<<256, 256, 0, stream>>>(Wv_c, Wp_c, mvp);
  bvp_build<<<1, 256, 0, stream>>>(bv_c, Wp_c, bp_c, bvp);

  // 3. features -> kn, vn (coalesced transpose + PE + two LayerNorms)
  ln_transpose2<<<B_ * 88, 256, 0, stream>>>(features, cross_pe,
      ln_kv_g, ln_kv_b, ln_vc_g, ln_vc_b, kn, vn);

  // 4. qn_c = LN(pooled); q~ = qn_c @ Mqk^T + bqk  -> [BW_,2048] bf16
  ln_rows<<<BW_, 256, 0, stream>>>(pooled, nullptr, 1, ln_qc_g, ln_qc_b, qn_c);
  gemm_bt<<<(BW_ / 64) * (2048 / 64), 256, 0, stream>>>(qn_c, mqk, BW_, 2048, 256,
      bqk, nullptr, nullptr, qt, 0);

  // 5. cross attention core -> ctx [BW_,2048] bf16
  cross_attn2<<<BW_, 256, 0, stream>>>(qt, kn, vn, ctx);

  // 6. x1 = ctx @ Mvp^T + bvp + pooled (f32)   [folded Wv@Wp projection]
  gemm_bt<<<(BW_ / 64) * (C_ / 64), 256, 0, stream>>>(ctx, mvp, BW_, C_, 2048,
      bvp, pooled, x1, nullptr, 0);

  // 7. qn_s = LN(x1 + self_pe); vn_s = LN(x1)
  ln_rows<<<BW_, 256, 0, stream>>>(x1, self_pe, W_, ln_qs_g, ln_qs_b, qn_s);
  ln_rows<<<BW_, 256, 0, stream>>>(x1, nullptr, 1, ln_vs_g, ln_vs_b, vn_s);

  // 8. q_s, k_s, v_s projections (f32 out)
  gemm_bt<<<(BW_ / 64) * (C_ / 64), 256, 0, stream>>>(qn_s, wqs, BW_, C_, C_,
      bq_s, nullptr, q_s, nullptr, 0);
  gemm_bt<<<(BW_ / 64) * (C_ / 64), 256, 0, stream>>>(qn_s, wks, BW_, C_, C_,
      nullptr, nullptr, k_s, nullptr, 0);
  gemm_bt<<<(BW_ / 64) * (C_ / 64), 256, 0, stream>>>(vn_s, wvs, BW_, C_, C_,
      bv_s, nullptr, v_s, nullptr, 0);

  // 9. self attention core
  self_attn<<<B_ * 8, 128, 0, stream>>>(q_s, k_s, v_s, s_o);

  // 10. x2 = s_o @ Wp_s + bp_s + x1
  gemm_bt<<<(BW_ / 64) * (C_ / 64), 256, 0, stream>>>(s_o, wps, BW_, C_, C_,
      bp_s, x1, x2, nullptr, 0);

  // 11. FFN: h1 = gelu(LN(x2) @ W1 + b1); out = h1 @ W2 + b2 + x2
  ln_rows<<<BW_, 256, 0, stream>>>(x2, nullptr, 1, ln_ffn_g, ln_ffn_b, ffn_n);
  gemm_bt<<<(BW_ / 64) * (F_ / 64), 256, 0, stream>>>(ffn_n, w1t, BW_, F_, C_,
      b1, nullptr, nullptr, h1, 1);
  gemm_bt<<<(BW_ / 64) * (C_ / 64), 256, 0, stream>>>(h1, w2t, BW_, C_, F_,
      b2, x2, outp, nullptr, 0);
}

// Round 3
// 562.555 us; speedup vs baseline: 1.1803x; 1.0560x over previous
//
#include <hip/hip_runtime.h>
#include <math.h>

// Problem dims
#define B_   48
#define W_   88
#define C_   256
#define H_   32
#define F_   1024
#define BW_  (B_ * W_)        // 4224
#define BWH_ (B_ * W_ * H_)   // 135168
#define HW_  (H_ * W_)        // 2816

typedef float  f32x4  __attribute__((ext_vector_type(4)));
typedef __bf16 bf16x8 __attribute__((ext_vector_type(8)));

__device__ __forceinline__ unsigned short f2bf(float f) {
  union { float f; unsigned int u; } v; v.f = f;
  unsigned int r = v.u + 0x7FFFu + ((v.u >> 16) & 1u);  // RNE
  return (unsigned short)(r >> 16);
}
__device__ __forceinline__ float bf2f(unsigned short h) {
  union { unsigned int u; float f; } v; v.u = ((unsigned int)h) << 16;
  return v.f;
}
__device__ __forceinline__ unsigned int pack2(float a, float b) {
  return (unsigned int)f2bf(a) | ((unsigned int)f2bf(b) << 16);
}

// ---------------------------------------------------------------------------
// wt_all: all weight transposes f32[in,out] -> bf16[out,in] in ONE launch.
// wqks = concat(Wq_s^T, Wk_s^T) [512,256]; bqks = concat(bq_s, 0) f32[512].
// ---------------------------------------------------------------------------
__global__ __launch_bounds__(256) void wt_all(
    const float* __restrict__ Wq_s, const float* __restrict__ Wk_s,
    const float* __restrict__ Wv_s, const float* __restrict__ Wp_s,
    const float* __restrict__ W1, const float* __restrict__ W2,
    const float* __restrict__ bq_s,
    unsigned short* __restrict__ wqks, unsigned short* __restrict__ wvs,
    unsigned short* __restrict__ wps, unsigned short* __restrict__ w1t,
    unsigned short* __restrict__ w2t, float* __restrict__ bqks) {
  int blk = blockIdx.x, t = threadIdx.x;
  if (blk < 256) {
    int idx = blk * 256 + t; int o = idx >> 8, i = idx & 255;
    wqks[idx] = f2bf(Wq_s[i * 256 + o]);
  } else if (blk < 512) {
    int idx = (blk - 256) * 256 + t; int o = idx >> 8, i = idx & 255;
    wqks[65536 + idx] = f2bf(Wk_s[i * 256 + o]);
  } else if (blk < 768) {
    int idx = (blk - 512) * 256 + t; int o = idx >> 8, i = idx & 255;
    wvs[idx] = f2bf(Wv_s[i * 256 + o]);
  } else if (blk < 1024) {
    int idx = (blk - 768) * 256 + t; int o = idx >> 8, i = idx & 255;
    wps[idx] = f2bf(Wp_s[i * 256 + o]);
  } else if (blk < 2048) {
    int idx = (blk - 1024) * 256 + t; int o = idx >> 8, i = idx & 255;
    w1t[idx] = f2bf(W1[i * 1024 + o]);
  } else if (blk < 3072) {
    int idx = (blk - 2048) * 256 + t; int o = idx >> 10, i = idx & 1023;
    w2t[idx] = f2bf(W2[i * 256 + o]);
  } else {
    bqks[t] = bq_s[t];
    bqks[256 + t] = 0.f;
  }
}

// ---------------------------------------------------------------------------
// mqk_build2: Mqk[n=256h+c][d'] = scale * sum_dd Wq[d',32h+dd]*Wk[c,32h+dd]
// Coalesced staged version. Block = (h, c-chunk of 32). 64 blocks.
// ---------------------------------------------------------------------------
__global__ __launch_bounds__(256) void mqk_build2(
    const float* __restrict__ Wq, const float* __restrict__ Wk,
    const float* __restrict__ bq,
    unsigned short* __restrict__ Mqk, float* __restrict__ bqk) {
  int h  = blockIdx.x >> 3;
  int cb = blockIdx.x & 7;
  __shared__ float wq_s[256][33];
  int t = threadIdx.x;
  int r0 = t >> 3, d4 = (t & 7) * 4;
#pragma unroll
  for (int j = 0; j < 8; j++) {
    int dp = r0 + j * 32;
    float4 v = *(const float4*)(Wq + (size_t)dp * 256 + 32 * h + d4);
    wq_s[dp][d4 + 0] = v.x; wq_s[dp][d4 + 1] = v.y;
    wq_s[dp][d4 + 2] = v.z; wq_s[dp][d4 + 3] = v.w;
  }
  int c_l = t >> 3, ln = t & 7;
  float wk[32];
  const float* wkr = Wk + (size_t)(32 * cb + c_l) * 256 + 32 * h;
#pragma unroll
  for (int j = 0; j < 8; j++) {
    float4 v = *(const float4*)(wkr + j * 4);
    wk[j * 4 + 0] = v.x; wk[j * 4 + 1] = v.y; wk[j * 4 + 2] = v.z; wk[j * 4 + 3] = v.w;
  }
  __syncthreads();
  const float scale = 0.17677669529663689f;
  int n = 256 * h + 32 * cb + c_l;
  for (int i = 0; i < 32; i++) {
    int dp = 8 * i + ln;
    float acc = 0.f;
#pragma unroll
    for (int dd = 0; dd < 32; dd++) acc += wq_s[dp][dd] * wk[dd];
    Mqk[(size_t)n * 256 + dp] = f2bf(acc * scale);
  }
  if (ln == 0) {
    float bb = 0.f;
#pragma unroll
    for (int dd = 0; dd < 32; dd++) bb += bq[32 * h + dd] * wk[dd];
    bqk[n] = bb * scale;
  }
}

// ---------------------------------------------------------------------------
// mvp_build2: Mvp[d][k=256h+c] = sum_dd Wv[c,32h+dd]*Wp[32h+dd,d]
// Block = (h, d-chunk of 32). 64 blocks.
// ---------------------------------------------------------------------------
__global__ __launch_bounds__(256) void mvp_build2(
    const float* __restrict__ Wv, const float* __restrict__ Wp,
    unsigned short* __restrict__ Mvp) {
  int h  = blockIdx.x >> 3;
  int db = blockIdx.x & 7;
  __shared__ float wv_s[256][33];
  int t = threadIdx.x;
  int r0 = t >> 3, d4 = (t & 7) * 4;
#pragma unroll
  for (int j = 0; j < 8; j++) {
    int c = r0 + j * 32;
    float4 v = *(const float4*)(Wv + (size_t)c * 256 + 32 * h + d4);
    wv_s[c][d4 + 0] = v.x; wv_s[c][d4 + 1] = v.y;
    wv_s[c][d4 + 2] = v.z; wv_s[c][d4 + 3] = v.w;
  }
  int d_l = t >> 3, ln = t & 7;
  int d = 32 * db + d_l;
  float wp[32];
#pragma unroll
  for (int dd = 0; dd < 32; dd++) wp[dd] = Wp[(size_t)(32 * h + dd) * 256 + d];
  __syncthreads();
  for (int i = 0; i < 32; i++) {
    int c = 8 * i + ln;
    float acc = 0.f;
#pragma unroll
    for (int dd = 0; dd < 32; dd++) acc += wv_s[c][dd] * wp[dd];
    Mvp[(size_t)d * 2048 + 256 * h + c] = f2bf(acc);
  }
}

__global__ void bvp_build(const float* __restrict__ bv, const float* __restrict__ Wp,
                          const float* __restrict__ bp, float* __restrict__ bvp) {
  int d = threadIdx.x;
  float acc = bp[d];
  for (int dp = 0; dp < 256; dp++) acc += bv[dp] * Wp[dp * 256 + d];
  bvp[d] = acc;
}

// ---------------------------------------------------------------------------
// ln_transpose3: features [B,C,H,W] -> kn = LN(kv+pe), vn = LN(kv), bf16
// rows [(b*W+w)*H+h][C].  Transposed LDS tile, registers, packed uint4 stores.
// ---------------------------------------------------------------------------
__global__ __launch_bounds__(256) void ln_transpose3(
    const float* __restrict__ features, const float* __restrict__ cross_pe,
    const float* __restrict__ g_kv, const float* __restrict__ b_kv,
    const float* __restrict__ g_vc, const float* __restrict__ b_vc,
    unsigned short* __restrict__ kn, unsigned short* __restrict__ vn) {
  int b   = blockIdx.x / 88;
  int tl  = blockIdx.x % 88;
  int hw0 = tl * 32;
  __shared__ float tileT[256][33];  // [c][row]
  int tid = threadIdx.x;
  // ---- load: fully-coalesced float4 over hw ----
  {
    int l4 = (tid & 7) * 4;
    int cc = tid >> 3;
    const float* fb = features + (size_t)b * C_ * HW_ + hw0;
#pragma unroll
    for (int p = 0; p < 8; p++) {
      int c = cc + p * 32;
      float4 v = *(const float4*)(fb + (size_t)c * HW_ + l4);
      tileT[c][l4 + 0] = v.x; tileT[c][l4 + 1] = v.y;
      tileT[c][l4 + 2] = v.z; tileT[c][l4 + 3] = v.w;
    }
  }
  __syncthreads();
  // ---- thread = (row, 1/8 of c). values -> registers ----
  int row = tid >> 3, ln = tid & 7;
  int hw = hw0 + row;
  int hh = hw / 88, ww = hw - hh * 88;
  const float* per = cross_pe + hh * 256;
  float vreg[32], preg[32];
  float s1 = 0, s2 = 0, p1 = 0, p2 = 0;
#pragma unroll
  for (int k = 0; k < 4; k++) {
    int c0 = k * 64 + ln * 8;
    float4 pa = *(const float4*)(per + c0);
    float4 pb = *(const float4*)(per + c0 + 4);
    float pv[8] = {pa.x, pa.y, pa.z, pa.w, pb.x, pb.y, pb.z, pb.w};
#pragma unroll
    for (int i = 0; i < 8; i++) {
      float v  = tileT[c0 + i][row];
      float vp = v + pv[i];
      vreg[k * 8 + i] = v; preg[k * 8 + i] = pv[i];
      s1 += v;  s2 += v * v;
      p1 += vp; p2 += vp * vp;
    }
  }
#pragma unroll
  for (int m = 1; m < 8; m <<= 1) {
    s1 += __shfl_xor(s1, m, 8); s2 += __shfl_xor(s2, m, 8);
    p1 += __shfl_xor(p1, m, 8); p2 += __shfl_xor(p2, m, 8);
  }
  float mu  = s1 * (1.f / 256.f);
  float rs  = rsqrtf(s2 * (1.f / 256.f) - mu * mu + 1e-5f);
  float muk = p1 * (1.f / 256.f);
  float rsk = rsqrtf(p2 * (1.f / 256.f) - muk * muk + 1e-5f);
  size_t ro = ((size_t)b * 88 + ww) * 32 + hh;
#pragma unroll
  for (int k = 0; k < 4; k++) {
    int c0 = k * 64 + ln * 8;
    float gv[8], bv8[8], gk8[8], bk8[8];
    *(float4*)&gv[0]  = *(const float4*)(g_vc + c0); *(float4*)&gv[4]  = *(const float4*)(g_vc + c0 + 4);
    *(float4*)&bv8[0] = *(const float4*)(b_vc + c0); *(float4*)&bv8[4] = *(const float4*)(b_vc + c0 + 4);
    *(float4*)&gk8[0] = *(const float4*)(g_kv + c0); *(float4*)&gk8[4] = *(const float4*)(g_kv + c0 + 4);
    *(float4*)&bk8[0] = *(const float4*)(b_kv + c0); *(float4*)&bk8[4] = *(const float4*)(b_kv + c0 + 4);
    uint4 uv, uk;
    unsigned int pv_[4], pk_[4];
#pragma unroll
    for (int i = 0; i < 8; i += 2) {
      float cg0 = gv[i] * rs, cg1 = gv[i + 1] * rs;
      float o0 = fmaf(vreg[k * 8 + i],     cg0, fmaf(-mu, cg0, bv8[i]));
      float o1 = fmaf(vreg[k * 8 + i + 1], cg1, fmaf(-mu, cg1, bv8[i + 1]));
      pv_[i >> 1] = pack2(o0, o1);
      float ck0 = gk8[i] * rsk, ck1 = gk8[i + 1] * rsk;
      float q0 = fmaf(vreg[k * 8 + i],     ck0, fmaf(preg[k * 8 + i] - muk,     ck0, bk8[i]));
      float q1 = fmaf(vreg[k * 8 + i + 1], ck1, fmaf(preg[k * 8 + i + 1] - muk, ck1, bk8[i + 1]));
      pk_[i >> 1] = pack2(q0, q1);
    }
    uv.x = pv_[0]; uv.y = pv_[1]; uv.z = pv_[2]; uv.w = pv_[3];
    uk.x = pk_[0]; uk.y = pk_[1]; uk.z = pk_[2]; uk.w = pk_[3];
    *(uint4*)(vn + ro * 256 + c0) = uv;
    *(uint4*)(kn + ro * 256 + c0) = uk;
  }
}

// ---------------------------------------------------------------------------
// Row LayerNorm: x f32 [rows, C_] -> bf16 out
// ---------------------------------------------------------------------------
__global__ __launch_bounds__(256) void ln_rows(
    const float* __restrict__ x,
    const float* __restrict__ g, const float* __restrict__ bta,
    unsigned short* __restrict__ out) {
  int row = blockIdx.x, c = threadIdx.x;
  float v = x[(size_t)row * C_ + c];
  float s1 = v, s2 = v * v;
#pragma unroll
  for (int m = 32; m > 0; m >>= 1) {
    s1 += __shfl_xor(s1, m, 64);
    s2 += __shfl_xor(s2, m, 64);
  }
  __shared__ float red[8];
  int wave = c >> 6;
  if ((c & 63) == 0) { red[wave] = s1; red[4 + wave] = s2; }
  __syncthreads();
  s1 = red[0] + red[1] + red[2] + red[3];
  s2 = red[4] + red[5] + red[6] + red[7];
  float mu = s1 * (1.f / C_);
  float rs = rsqrtf(s2 * (1.f / C_) - mu * mu + 1e-5f);
  out[(size_t)row * C_ + c] = f2bf((v - mu) * rs * g[c] + bta[c]);
}

// ---------------------------------------------------------------------------
// ln_dual: out1 = LN(x+pe)*g1+b1 (qn_s), out2 = LN(x)*g2+b2 (vn_s). One read.
// ---------------------------------------------------------------------------
__global__ __launch_bounds__(256) void ln_dual(
    const float* __restrict__ x, const float* __restrict__ pe,
    const float* __restrict__ g1, const float* __restrict__ b1a,
    const float* __restrict__ g2, const float* __restrict__ b2a,
    unsigned short* __restrict__ out1, unsigned short* __restrict__ out2) {
  int row = blockIdx.x, c = threadIdx.x;
  float v = x[(size_t)row * C_ + c];
  float vp = v + pe[(size_t)(row % 88) * C_ + c];
  float s1 = v, s2 = v * v, t1 = vp, t2 = vp * vp;
#pragma unroll
  for (int m = 32; m > 0; m >>= 1) {
    s1 += __shfl_xor(s1, m, 64); s2 += __shfl_xor(s2, m, 64);
    t1 += __shfl_xor(t1, m, 64); t2 += __shfl_xor(t2, m, 64);
  }
  __shared__ float red[16];
  int wave = c >> 6;
  if ((c & 63) == 0) {
    red[wave] = s1; red[4 + wave] = s2; red[8 + wave] = t1; red[12 + wave] = t2;
  }
  __syncthreads();
  s1 = red[0] + red[1] + red[2] + red[3];
  s2 = red[4] + red[5] + red[6] + red[7];
  t1 = red[8] + red[9] + red[10] + red[11];
  t2 = red[12] + red[13] + red[14] + red[15];
  float mu = s1 * (1.f / C_), rs = rsqrtf(s2 * (1.f / C_) - mu * mu + 1e-5f);
  float mup = t1 * (1.f / C_), rsp = rsqrtf(t2 * (1.f / C_) - mup * mup + 1e-5f);
  out1[(size_t)row * C_ + c] = f2bf((vp - mup) * rsp * g1[c] + b1a[c]);
  out2[(size_t)row * C_ + c] = f2bf((v - mu) * rs * g2[c] + b2a[c]);
}

// ---------------------------------------------------------------------------
// GEMM: out[M,N] = A[M,K](bf16) @ Bt[N,K](bf16)^T, fp32 acc.
// ---------------------------------------------------------------------------
__global__ __launch_bounds__(256) void gemm_bt(
    const unsigned short* __restrict__ A, const unsigned short* __restrict__ Bt,
    int M, int N, int K,
    const float* __restrict__ bias, const float* __restrict__ resid,
    float* __restrict__ outF, unsigned short* __restrict__ outB, int act_gelu) {
  __shared__ __attribute__((aligned(16))) unsigned short As[64][32];
  __shared__ __attribute__((aligned(16))) unsigned short Bs[64][32];
  const int tiles_n = N >> 6;
  const int bm = blockIdx.x / tiles_n;
  const int bn = blockIdx.x % tiles_n;
  const int tid = threadIdx.x;
  const int wave = tid >> 6, lane = tid & 63;
  const int quad = lane >> 4, lr = lane & 15;
  const int wm = (wave >> 1) << 5, wn = (wave & 1) << 5;
  const int lrow = tid >> 2;
  const int lcol = (tid & 3) << 3;
  const size_t a_base = (size_t)(bm * 64 + lrow) * K + lcol;
  const size_t b_base = (size_t)(bn * 64 + lrow) * K + lcol;
  f32x4 acc[2][2] = {};
  for (int k0 = 0; k0 < K; k0 += 32) {
    *(uint4*)&As[lrow][lcol] = *(const uint4*)(A + a_base + k0);
    *(uint4*)&Bs[lrow][lcol] = *(const uint4*)(Bt + b_base + k0);
    __syncthreads();
    bf16x8 af0 = *(const bf16x8*)&As[wm + lr][quad << 3];
    bf16x8 af1 = *(const bf16x8*)&As[wm + 16 + lr][quad << 3];
    bf16x8 bf0 = *(const bf16x8*)&Bs[wn + lr][quad << 3];
    bf16x8 bf1 = *(const bf16x8*)&Bs[wn + 16 + lr][quad << 3];
    acc[0][0] = __builtin_amdgcn_mfma_f32_16x16x32_bf16(af0, bf0, acc[0][0], 0, 0, 0);
    acc[0][1] = __builtin_amdgcn_mfma_f32_16x16x32_bf16(af0, bf1, acc[0][1], 0, 0, 0);
    acc[1][0] = __builtin_amdgcn_mfma_f32_16x16x32_bf16(af1, bf0, acc[1][0], 0, 0, 0);
    acc[1][1] = __builtin_amdgcn_mfma_f32_16x16x32_bf16(af1, bf1, acc[1][1], 0, 0, 0);
    __syncthreads();
  }
#pragma unroll
  for (int i = 0; i < 2; i++)
#pragma unroll
    for (int j = 0; j < 2; j++)
#pragma unroll
      for (int rr = 0; rr < 4; rr++) {
        int row = bm * 64 + wm + i * 16 + quad * 4 + rr;
        int col = bn * 64 + wn + j * 16 + lr;
        float val = acc[i][j][rr];
        if (bias) val += bias[col];
        if (act_gelu) val = 0.5f * val * (1.f + erff(val * 0.70710678118654752f));
        if (resid) val += resid[(size_t)row * N + col];
        if (outF) outF[(size_t)row * N + col] = val;
        else outB[(size_t)row * N + col] = f2bf(val);
      }
}

// ---------------------------------------------------------------------------
// cross_attn2: per (b,w). qt [BW_,2048] bf16; kn/vn [BWH_,256] bf16.
// ---------------------------------------------------------------------------
#define KSTR 264
__global__ __launch_bounds__(256) void cross_attn2(
    const unsigned short* __restrict__ qt_g,
    const unsigned short* __restrict__ kn, const unsigned short* __restrict__ vn,
    unsigned short* __restrict__ ctx_g) {
  int bw = blockIdx.x;
  int tid = threadIdx.x;
  __shared__ __attribute__((aligned(16))) unsigned short qtl[8][KSTR];
  __shared__ __attribute__((aligned(16))) unsigned short knl[32][KSTR];
  __shared__ __attribute__((aligned(16))) unsigned short vnl[32][KSTR];
  __shared__ float s_sc[32 * 9];
  __shared__ float ps[8 * 36];
  __shared__ __attribute__((aligned(16))) unsigned short ctxl[2048];
  {
    uint4 qv = *(const uint4*)(qt_g + (size_t)bw * 2048 + tid * 8);
    int h = tid >> 5, c0 = (tid & 31) * 8;
    *(uint4*)&qtl[h][c0] = qv;
    int j = tid >> 3, cs = (tid & 7) * 32;
    const unsigned short* kr = kn + ((size_t)bw * 32 + j) * 256 + cs;
    const unsigned short* vr = vn + ((size_t)bw * 32 + j) * 256 + cs;
#pragma unroll
    for (int k = 0; k < 4; k++) {
      *(uint4*)&knl[j][cs + k * 8] = *(const uint4*)(kr + k * 8);
      *(uint4*)&vnl[j][cs + k * 8] = *(const uint4*)(vr + k * 8);
    }
  }
  __syncthreads();
  {
    int j = tid >> 3, h = tid & 7;
    float acc = 0.f;
#pragma unroll
    for (int c8 = 0; c8 < 32; c8++) {
      bf16x8 kk = *(const bf16x8*)&knl[j][c8 * 8];
      bf16x8 qq = *(const bf16x8*)&qtl[h][c8 * 8];
#pragma unroll
      for (int i = 0; i < 8; i++) acc += (float)qq[i] * (float)kk[i];
    }
    s_sc[j * 9 + h] = acc;
  }
  __syncthreads();
  {
    int h = tid >> 5, j = tid & 31;
    float s = s_sc[j * 9 + h];
    float mx = s;
#pragma unroll
    for (int m = 16; m > 0; m >>= 1) mx = fmaxf(mx, __shfl_xor(mx, m, 32));
    float e = __expf(s - mx);
    float sum = e;
#pragma unroll
    for (int m = 16; m > 0; m >>= 1) sum += __shfl_xor(sum, m, 32);
    ps[h * 36 + j] = e / sum;
  }
  __syncthreads();
  {
    int h = tid & 7, c0 = (tid >> 3) * 8;
    float acc[8];
#pragma unroll
    for (int i = 0; i < 8; i++) acc[i] = 0.f;
#pragma unroll 8
    for (int j = 0; j < 32; j++) {
      float p = ps[h * 36 + j];
      bf16x8 vv = *(const bf16x8*)&vnl[j][c0];
#pragma unroll
      for (int i = 0; i < 8; i++) acc[i] += p * (float)vv[i];
    }
    unsigned short pk[8];
#pragma unroll
    for (int i = 0; i < 8; i++) pk[i] = f2bf(acc[i]);
    *(uint4*)&ctxl[h * 256 + c0] = *(uint4*)pk;
  }
  __syncthreads();
  *(uint4*)(ctx_g + (size_t)bw * 2048 + tid * 8) = *(const uint4*)&ctxl[tid * 8];
}

// ---------------------------------------------------------------------------
// self_attn2: block = (b, head, half); 44 query rows over 88 keys, d=32.
// qk [BW_,512] f32 (q cols 0..255, k cols 256..511); v [BW_,256] f32.
// ---------------------------------------------------------------------------
__global__ __launch_bounds__(64) void self_attn2(
    const float* __restrict__ qk, const float* __restrict__ v,
    unsigned short* __restrict__ out) {
  int blk = blockIdx.x;
  int half = blk & 1, h = (blk >> 1) & 7, b = blk >> 4;
  __shared__ float kl[88][32];
  __shared__ float vl[88][32];
  __shared__ float sc[44][89];
  int t = threadIdx.x;
  for (int i = t; i < 704; i += 64) {
    int m = i >> 3, d4 = (i & 7) << 2;
    *(float4*)&kl[m][d4] = *(const float4*)(qk + ((size_t)(b * 88 + m)) * 512 + 256 + h * 32 + d4);
    *(float4*)&vl[m][d4] = *(const float4*)(v + ((size_t)(b * 88 + m)) * 256 + h * 32 + d4);
  }
  __syncthreads();
  if (t < 44) {
    int r = half * 44 + t;
    const float* qrow = qk + ((size_t)(b * 88 + r)) * 512 + h * 32;
    float qr[32];
#pragma unroll
    for (int d = 0; d < 32; d++) qr[d] = qrow[d];
    float mx = -1e30f;
    for (int m = 0; m < 88; m++) {
      float s = 0.f;
#pragma unroll
      for (int d = 0; d < 32; d++) s += qr[d] * kl[m][d];
      s *= 0.17677669529663689f;
      sc[t][m] = s;
      mx = fmaxf(mx, s);
    }
    float sum = 0.f;
    for (int m = 0; m < 88; m++) { float e = __expf(sc[t][m] - mx); sc[t][m] = e; sum += e; }
    float inv = 1.f / sum;
    float o[32];
#pragma unroll
    for (int d = 0; d < 32; d++) o[d] = 0.f;
    for (int m = 0; m < 88; m++) {
      float p = sc[t][m] * inv;
#pragma unroll
      for (int d = 0; d < 32; d++) o[d] += p * vl[m][d];
    }
    unsigned short* orow = out + ((size_t)(b * 88 + r)) * 256 + h * 32;
#pragma unroll
    for (int g = 0; g < 4; g++) {
      uint4 u;
      u.x = pack2(o[g * 8 + 0], o[g * 8 + 1]);
      u.y = pack2(o[g * 8 + 2], o[g * 8 + 3]);
      u.z = pack2(o[g * 8 + 4], o[g * 8 + 5]);
      u.w = pack2(o[g * 8 + 6], o[g * 8 + 7]);
      *(uint4*)(orow + g * 8) = u;
    }
  }
}

// ---------------------------------------------------------------------------
extern "C" void kernel_launch(void* const* d_in, const int* in_sizes, int n_in,
                              void* d_out, int out_size, void* d_ws, size_t ws_size,
                              hipStream_t stream) {
  (void)in_sizes; (void)n_in; (void)out_size; (void)ws_size;
  const float* pooled   = (const float*)d_in[0];
  const float* features = (const float*)d_in[1];
  const float* self_pe  = (const float*)d_in[2];
  const float* cross_pe = (const float*)d_in[3];
  const float* ln_qs_g = (const float*)d_in[4],  *ln_qs_b = (const float*)d_in[5];
  const float* ln_vs_g = (const float*)d_in[6],  *ln_vs_b = (const float*)d_in[7];
  const float* ln_qc_g = (const float*)d_in[8],  *ln_qc_b = (const float*)d_in[9];
  const float* ln_kv_g = (const float*)d_in[10], *ln_kv_b = (const float*)d_in[11];
  const float* ln_vc_g = (const float*)d_in[12], *ln_vc_b = (const float*)d_in[13];
  const float* ln_ffn_g = (const float*)d_in[14], *ln_ffn_b = (const float*)d_in[15];
  const float* Wq_s = (const float*)d_in[16], *Wk_s = (const float*)d_in[17];
  const float* Wv_s = (const float*)d_in[18], *Wp_s = (const float*)d_in[19];
  const float* Wq_c = (const float*)d_in[20], *Wk_c = (const float*)d_in[21];
  const float* Wv_c = (const float*)d_in[22], *Wp_c = (const float*)d_in[23];
  const float* bq_s = (const float*)d_in[24], *bv_s = (const float*)d_in[25];
  const float* bp_s = (const float*)d_in[26], *bq_c = (const float*)d_in[27];
  const float* bv_c = (const float*)d_in[28], *bp_c = (const float*)d_in[29];
  const float* W1 = (const float*)d_in[30], *b1 = (const float*)d_in[31];
  const float* W2 = (const float*)d_in[32], *b2 = (const float*)d_in[33];
  float* outp = (float*)d_out;
  char* ws = (char*)d_ws;

  // ---- workspace layout ----
  size_t off = 0;
  auto alloc = [&](size_t bytes) { size_t o = off; off = (off + bytes + 255) & ~(size_t)255; return o; };
  const size_t big = (size_t)BWH_ * C_ * 2;          // 69.2 MB each
  size_t KN  = alloc(big);
  size_t VN  = alloc(big);
  size_t QT  = alloc((size_t)BW_ * 2048 * 2);
  size_t CTX = alloc((size_t)BW_ * 2048 * 2);
  size_t MQK = alloc((size_t)2048 * 256 * 2);
  size_t MVP = alloc((size_t)256 * 2048 * 2);
  size_t BQK = alloc(2048 * 4);
  size_t BVP = alloc(256 * 4);
  size_t WQKS = alloc((size_t)512 * 256 * 2);
  size_t BQKS = alloc(512 * 4);
  size_t WVS = alloc(65536 * 2), WPS = alloc(65536 * 2);
  size_t W1T = alloc(262144 * 2), W2T = alloc(262144 * 2);
  size_t QN_C = alloc((size_t)BW_ * C_ * 2);
  // phase-B overlays KN/VN region (dead after cross_attn2)
  size_t offp = KN;
  auto allocP = [&](size_t bytes) { size_t o = offp; offp = (offp + bytes + 255) & ~(size_t)255; return o; };
  size_t X1   = allocP((size_t)BW_ * C_ * 4);
  size_t QN_S = allocP((size_t)BW_ * C_ * 2);
  size_t VN_S = allocP((size_t)BW_ * C_ * 2);
  size_t QK_S = allocP((size_t)BW_ * 512 * 4);
  size_t V_S  = allocP((size_t)BW_ * C_ * 4);
  size_t S_O  = allocP((size_t)BW_ * C_ * 2);
  size_t X2   = allocP((size_t)BW_ * C_ * 4);
  size_t FFN  = allocP((size_t)BW_ * C_ * 2);
  size_t H1   = allocP((size_t)BW_ * F_ * 2);

  unsigned short* kn   = (unsigned short*)(ws + KN);
  unsigned short* vn   = (unsigned short*)(ws + VN);
  unsigned short* qt   = (unsigned short*)(ws + QT);
  unsigned short* ctx  = (unsigned short*)(ws + CTX);
  unsigned short* mqk  = (unsigned short*)(ws + MQK);
  unsigned short* mvp  = (unsigned short*)(ws + MVP);
  float* bqk = (float*)(ws + BQK);
  float* bvp = (float*)(ws + BVP);
  unsigned short* wqks = (unsigned short*)(ws + WQKS);
  float* bqks = (float*)(ws + BQKS);
  unsigned short* wvs = (unsigned short*)(ws + WVS), *wps = (unsigned short*)(ws + WPS);
  unsigned short* w1t = (unsigned short*)(ws + W1T), *w2t = (unsigned short*)(ws + W2T);
  unsigned short* qn_c = (unsigned short*)(ws + QN_C);
  float*          x1   = (float*)(ws + X1);
  unsigned short* qn_s = (unsigned short*)(ws + QN_S);
  unsigned short* vn_s = (unsigned short*)(ws + VN_S);
  float* qk_s = (float*)(ws + QK_S);
  float* v_s  = (float*)(ws + V_S);
  unsigned short* s_o  = (unsigned short*)(ws + S_O);
  float*          x2   = (float*)(ws + X2);
  unsigned short* ffn_n = (unsigned short*)(ws + FFN);
  unsigned short* h1    = (unsigned short*)(ws + H1);

  // 1. all weight prep in one launch
  wt_all<<<3073, 256, 0, stream>>>(Wq_s, Wk_s, Wv_s, Wp_s, W1, W2, bq_s,
                                   wqks, wvs, wps, w1t, w2t, bqks);
  // 2. folded cross-attention matrices (coalesced)
  mqk_build2<<<64, 256, 0, stream>>>(Wq_c, Wk_c, bq_c, mqk, bqk);
  mvp_build2<<<64, 256, 0, stream>>>(Wv_c, Wp_c, mvp);
  bvp_build<<<1, 256, 0, stream>>>(bv_c, Wp_c, bp_c, bvp);

  // 3. features -> kn, vn
  ln_transpose3<<<B_ * 88, 256, 0, stream>>>(features, cross_pe,
      ln_kv_g, ln_kv_b, ln_vc_g, ln_vc_b, kn, vn);

  // 4. qn_c = LN(pooled); q~ = qn_c @ Mqk^T + bqk
  ln_rows<<<BW_, 256, 0, stream>>>(pooled, ln_qc_g, ln_qc_b, qn_c);
  gemm_bt<<<(BW_ / 64) * (2048 / 64), 256, 0, stream>>>(qn_c, mqk, BW_, 2048, 256,
      bqk, nullptr, nullptr, qt, 0);

  // 5. cross attention core
  cross_attn2<<<BW_, 256, 0, stream>>>(qt, kn, vn, ctx);

  // 6. x1 = ctx @ Mvp^T + bvp + pooled
  gemm_bt<<<(BW_ / 64) * (C_ / 64), 256, 0, stream>>>(ctx, mvp, BW_, C_, 2048,
      bvp, pooled, x1, nullptr, 0);

  // 7. qn_s = LN(x1+self_pe), vn_s = LN(x1) in one pass
  ln_dual<<<BW_, 256, 0, stream>>>(x1, self_pe, ln_qs_g, ln_qs_b,
                                   ln_vs_g, ln_vs_b, qn_s, vn_s);

  // 8. fused q|k projection (N=512) + v projection
  gemm_bt<<<(BW_ / 64) * (512 / 64), 256, 0, stream>>>(qn_s, wqks, BW_, 512, 256,
      bqks, nullptr, qk_s, nullptr, 0);
  gemm_bt<<<(BW_ / 64) * (C_ / 64), 256, 0, stream>>>(vn_s, wvs, BW_, C_, 256,
      bv_s, nullptr, v_s, nullptr, 0);

  // 9. self attention core
  self_attn2<<<B_ * 16, 64, 0, stream>>>(qk_s, v_s, s_o);

  // 10. x2 = s_o @ Wp_s + bp_s + x1
  gemm_bt<<<(BW_ / 64) * (C_ / 64), 256, 0, stream>>>(s_o, wps, BW_, C_, C_,
      bp_s, x1, x2, nullptr, 0);

  // 11. FFN
  ln_rows<<<BW_, 256, 0, stream>>>(x2, ln_ffn_g, ln_ffn_b, ffn_n);
  gemm_bt<<<(BW_ / 64) * (F_ / 64), 256, 0, stream>>>(ffn_n, w1t, BW_, F_, C_,
      b1, nullptr, nullptr, h1, 1);
  gemm_bt<<<(BW_ / 64) * (C_ / 64), 256, 0, stream>>>(h1, w2t, BW_, C_, F_,
      b2, x2, outp, nullptr, 0);
}

// Round 5
// 532.737 us; speedup vs baseline: 1.2464x; 1.0560x over previous
//
#include <hip/hip_runtime.h>
#include <math.h>

// Problem dims
#define B_   48
#define W_   88
#define C_   256
#define H_   32
#define F_   1024
#define BW_  (B_ * W_)        // 4224
#define BWH_ (B_ * W_ * H_)   // 135168
#define HW_  (H_ * W_)        // 2816

typedef float  f32x4  __attribute__((ext_vector_type(4)));
typedef __bf16 bf16x8 __attribute__((ext_vector_type(8)));

__device__ __forceinline__ unsigned short f2bf(float f) {
  union { float f; unsigned int u; } v; v.f = f;
  unsigned int r = v.u + 0x7FFFu + ((v.u >> 16) & 1u);  // RNE
  return (unsigned short)(r >> 16);
}
__device__ __forceinline__ float bf2f(unsigned short h) {
  union { unsigned int u; float f; } v; v.u = ((unsigned int)h) << 16;
  return v.f;
}
__device__ __forceinline__ unsigned int pack2(float a, float b) {
  return (unsigned int)f2bf(a) | ((unsigned int)f2bf(b) << 16);
}

// ---------------------------------------------------------------------------
// prep_all: every weight-prep step in ONE launch.
//  blk [0,768)      : 32x32 LDS tile transposes f32[in,out] -> bf16[out,in]
//  blk [768,1280)   : Mqk build  (512 blocks: h x 64 c-chunks of 4)
//  blk [1280,1792)  : Mvp build  (512 blocks: h x 64 d-chunks of 4)
//  blk 1792         : bvp + bqkvs concat
//  blk [1793,6017)  : LN(pooled) -> qn_c bf16 (one row per block)
// ---------------------------------------------------------------------------
__global__ __launch_bounds__(256) void prep_all(
    const float* __restrict__ Wq_s, const float* __restrict__ Wk_s,
    const float* __restrict__ Wv_s, const float* __restrict__ Wp_s,
    const float* __restrict__ W1, const float* __restrict__ W2,
    const float* __restrict__ Wq_c, const float* __restrict__ Wk_c,
    const float* __restrict__ Wv_c, const float* __restrict__ Wp_c,
    const float* __restrict__ bq_s, const float* __restrict__ bv_s,
    const float* __restrict__ bq_c, const float* __restrict__ bv_c,
    const float* __restrict__ bp_c,
    const float* __restrict__ pooled,
    const float* __restrict__ ln_qc_g, const float* __restrict__ ln_qc_b,
    unsigned short* __restrict__ wqkvs, unsigned short* __restrict__ wps,
    unsigned short* __restrict__ w1t, unsigned short* __restrict__ w2t,
    unsigned short* __restrict__ mqk, unsigned short* __restrict__ mvp,
    float* __restrict__ bqk, float* __restrict__ bvp,
    float* __restrict__ bqkvs, unsigned short* __restrict__ qn_c) {
  __shared__ float smem[256 * 33 + 4 * 33];
  int blk = blockIdx.x, t = threadIdx.x;

  if (blk < 768) {
    // ---- weight tile transpose ----
    const float* src; unsigned short* dst; int Cc, R, tile;
    if (blk < 64)       { src = Wq_s; dst = wqkvs;          Cc = 256;  R = 256;  tile = blk; }
    else if (blk < 128) { src = Wk_s; dst = wqkvs + 65536;  Cc = 256;  R = 256;  tile = blk - 64; }
    else if (blk < 192) { src = Wv_s; dst = wqkvs + 131072; Cc = 256;  R = 256;  tile = blk - 128; }
    else if (blk < 256) { src = Wp_s; dst = wps;            Cc = 256;  R = 256;  tile = blk - 192; }
    else if (blk < 512) { src = W1;   dst = w1t;            Cc = 1024; R = 256;  tile = blk - 256; }
    else                { src = W2;   dst = w2t;            Cc = 256;  R = 1024; tile = blk - 512; }
    int tcn = Cc >> 5;
    int tr = tile / tcn, tc = tile % tcn;
    float (*lds)[33] = (float(*)[33])smem;
    int r = t >> 3, c4 = (t & 7) * 4;
    float4 v = *(const float4*)(src + (size_t)(tr * 32 + r) * Cc + tc * 32 + c4);
    lds[r][c4 + 0] = v.x; lds[r][c4 + 1] = v.y; lds[r][c4 + 2] = v.z; lds[r][c4 + 3] = v.w;
    __syncthreads();
    // dst[(tc*32+rd)][tr*32 + cd] = src[tr*32+cd][tc*32+rd]
    int rd = t >> 3, cd4 = (t & 7) * 4;
    unsigned int u0 = pack2(lds[cd4 + 0][rd], lds[cd4 + 1][rd]);
    unsigned int u1 = pack2(lds[cd4 + 2][rd], lds[cd4 + 3][rd]);
    uint2 u; u.x = u0; u.y = u1;
    *(uint2*)(dst + (size_t)(tc * 32 + rd) * R + tr * 32 + cd4) = u;
  } else if (blk < 1280) {
    // ---- Mqk[n=256h+c][dp] = scale * sum_dd Wq_c[dp,32h+dd]*Wk_c[c,32h+dd]
    int lb = blk - 768;
    int h = lb >> 6, cb = lb & 63;
    float (*wq)[33] = (float(*)[33])smem;               // [256 dp][32 dd]
    float (*wk)[33] = (float(*)[33])(smem + 256 * 33);  // [4 c][32 dd]
#pragma unroll
    for (int p = 0; p < 8; p++) {
      int dp = (t >> 3) + 32 * p, d4 = (t & 7) * 4;
      float4 v = *(const float4*)(Wq_c + (size_t)dp * 256 + 32 * h + d4);
      wq[dp][d4 + 0] = v.x; wq[dp][d4 + 1] = v.y; wq[dp][d4 + 2] = v.z; wq[dp][d4 + 3] = v.w;
    }
    if (t < 128) {
      int c_l = t >> 5, dd = t & 31;
      wk[c_l][dd] = Wk_c[(size_t)(cb * 4 + c_l) * 256 + 32 * h + dd];
    }
    __syncthreads();
    const float scale = 0.17677669529663689f;
    int c_l = t >> 6, ln = t & 63;
    int n = 256 * h + cb * 4 + c_l;
#pragma unroll
    for (int j = 0; j < 4; j++) {
      int dp = ln + 64 * j;
      float acc = 0.f;
#pragma unroll
      for (int dd = 0; dd < 32; dd++) acc += wq[dp][dd] * wk[c_l][dd];
      mqk[(size_t)n * 256 + dp] = f2bf(acc * scale);
    }
    if (ln == 0) {
      float bb = 0.f;
#pragma unroll
      for (int dd = 0; dd < 32; dd++) bb += bq_c[32 * h + dd] * wk[c_l][dd];
      bqk[n] = bb * scale;
    }
  } else if (blk < 1792) {
    // ---- Mvp[d][256h+c] = sum_dd Wv_c[c,32h+dd]*Wp_c[32h+dd,d]
    int lb = blk - 1280;
    int h = lb >> 6, db = lb & 63;
    float (*wv)[33] = (float(*)[33])smem;
    float (*wp)[33] = (float(*)[33])(smem + 256 * 33);
#pragma unroll
    for (int p = 0; p < 8; p++) {
      int c = (t >> 3) + 32 * p, d4 = (t & 7) * 4;
      float4 v = *(const float4*)(Wv_c + (size_t)c * 256 + 32 * h + d4);
      wv[c][d4 + 0] = v.x; wv[c][d4 + 1] = v.y; wv[c][d4 + 2] = v.z; wv[c][d4 + 3] = v.w;
    }
    if (t < 128) {
      int d_l = t >> 5, dd = t & 31;
      wp[d_l][dd] = Wp_c[(size_t)(32 * h + dd) * 256 + db * 4 + d_l];
    }
    __syncthreads();
    int d_l = t >> 6, ln = t & 63;
    int d = db * 4 + d_l;
#pragma unroll
    for (int j = 0; j < 4; j++) {
      int c = ln + 64 * j;
      float acc = 0.f;
#pragma unroll
      for (int dd = 0; dd < 32; dd++) acc += wv[c][dd] * wp[d_l][dd];
      mvp[(size_t)d * 2048 + 256 * h + c] = f2bf(acc);
    }
  } else if (blk == 1792) {
    // ---- bvp + bqkvs ----
    float acc = bp_c[t];
    for (int dp = 0; dp < 256; dp++) acc += bv_c[dp] * Wp_c[(size_t)dp * 256 + t];
    bvp[t] = acc;
    bqkvs[t] = bq_s[t]; bqkvs[256 + t] = 0.f; bqkvs[512 + t] = bv_s[t];
  } else {
    // ---- LN(pooled) row -> qn_c ----
    int row = blk - 1793, c = t;
    float v = pooled[(size_t)row * C_ + c];
    float s1 = v, s2 = v * v;
#pragma unroll
    for (int m = 32; m > 0; m >>= 1) {
      s1 += __shfl_xor(s1, m, 64); s2 += __shfl_xor(s2, m, 64);
    }
    float* red = smem;
    int wave = c >> 6;
    if ((c & 63) == 0) { red[wave] = s1; red[4 + wave] = s2; }
    __syncthreads();
    s1 = red[0] + red[1] + red[2] + red[3];
    s2 = red[4] + red[5] + red[6] + red[7];
    float mu = s1 * (1.f / C_);
    float rs = rsqrtf(s2 * (1.f / C_) - mu * mu + 1e-5f);
    qn_c[(size_t)row * C_ + c] = f2bf((v - mu) * rs * ln_qc_g[c] + ln_qc_b[c]);
  }
}

// ---------------------------------------------------------------------------
// ln_transpose4: features [B,C,H,W] -> kn = LN(kv+pe), vn = LN(kv), bf16
// rows [(b*W+w)*H+h][C]. 16-hw tiles, 17.4KB LDS, 2-way-free LDS reads.
// ---------------------------------------------------------------------------
__global__ __launch_bounds__(256) void ln_transpose4(
    const float* __restrict__ features, const float* __restrict__ cross_pe,
    const float* __restrict__ g_kv, const float* __restrict__ b_kv,
    const float* __restrict__ g_vc, const float* __restrict__ b_vc,
    unsigned short* __restrict__ kn, unsigned short* __restrict__ vn) {
  int b   = blockIdx.x / 176;
  int tl  = blockIdx.x % 176;
  int hw0 = tl * 16;
  __shared__ float tileT[256][17];
  int t = threadIdx.x;
  {
    int a  = (t & 3) * 4;
    int cc = t >> 2;  // 0..63
    const float* fb = features + (size_t)b * C_ * HW_ + hw0;
#pragma unroll
    for (int p = 0; p < 4; p++) {
      int c = cc + p * 64;
      float4 v = *(const float4*)(fb + (size_t)c * HW_ + a);
      tileT[c][a + 0] = v.x; tileT[c][a + 1] = v.y;
      tileT[c][a + 2] = v.z; tileT[c][a + 3] = v.w;
    }
  }
  __syncthreads();
  int row = t >> 4, ln = t & 15;
  int hw = hw0 + row;
  int hh = hw / 88, ww = hw - hh * 88;
  const float* per = cross_pe + hh * 256;
  float vreg[16], preg[16];
  float s1 = 0, s2 = 0, p1 = 0, p2 = 0;
#pragma unroll
  for (int j = 0; j < 4; j++) {
    int c0 = 4 * ln + 64 * j;
    float4 pv = *(const float4*)(per + c0);
    float pa[4] = {pv.x, pv.y, pv.z, pv.w};
#pragma unroll
    for (int i = 0; i < 4; i++) {
      float v  = tileT[c0 + i][row];
      float vp = v + pa[i];
      vreg[4 * j + i] = v; preg[4 * j + i] = pa[i];
      s1 += v;  s2 += v * v;
      p1 += vp; p2 += vp * vp;
    }
  }
#pragma unroll
  for (int m = 1; m < 16; m <<= 1) {
    s1 += __shfl_xor(s1, m, 16); s2 += __shfl_xor(s2, m, 16);
    p1 += __shfl_xor(p1, m, 16); p2 += __shfl_xor(p2, m, 16);
  }
  float mu  = s1 * (1.f / 256.f);
  float rs  = rsqrtf(s2 * (1.f / 256.f) - mu * mu + 1e-5f);
  float muk = p1 * (1.f / 256.f);
  float rsk = rsqrtf(p2 * (1.f / 256.f) - muk * muk + 1e-5f);
  size_t ro = ((size_t)b * 88 + ww) * 32 + hh;
  unsigned short* vrow = vn + ro * 256;
  unsigned short* krow = kn + ro * 256;
#pragma unroll
  for (int j = 0; j < 4; j++) {
    int c0 = 4 * ln + 64 * j;
    float4 gv = *(const float4*)(g_vc + c0);
    float4 bv = *(const float4*)(b_vc + c0);
    float4 gk = *(const float4*)(g_kv + c0);
    float4 bk = *(const float4*)(b_kv + c0);
    float gva[4] = {gv.x, gv.y, gv.z, gv.w}, bva[4] = {bv.x, bv.y, bv.z, bv.w};
    float gka[4] = {gk.x, gk.y, gk.z, gk.w}, bka[4] = {bk.x, bk.y, bk.z, bk.w};
    float ov[4], ok[4];
#pragma unroll
    for (int i = 0; i < 4; i++) {
      float v = vreg[4 * j + i], p = preg[4 * j + i];
      ov[i] = (v - mu) * rs * gva[i] + bva[i];
      ok[i] = (v + p - muk) * rsk * gka[i] + bka[i];
    }
    uint2 uv, uk;
    uv.x = pack2(ov[0], ov[1]); uv.y = pack2(ov[2], ov[3]);
    uk.x = pack2(ok[0], ok[1]); uk.y = pack2(ok[2], ok[3]);
    *(uint2*)(vrow + c0) = uv;
    *(uint2*)(krow + c0) = uk;
  }
}

// ---------------------------------------------------------------------------
// Row LayerNorm: x f32 [rows, C_] -> bf16 out
// ---------------------------------------------------------------------------
__global__ __launch_bounds__(256) void ln_rows(
    const float* __restrict__ x,
    const float* __restrict__ g, const float* __restrict__ bta,
    unsigned short* __restrict__ out) {
  int row = blockIdx.x, c = threadIdx.x;
  float v = x[(size_t)row * C_ + c];
  float s1 = v, s2 = v * v;
#pragma unroll
  for (int m = 32; m > 0; m >>= 1) {
    s1 += __shfl_xor(s1, m, 64);
    s2 += __shfl_xor(s2, m, 64);
  }
  __shared__ float red[8];
  int wave = c >> 6;
  if ((c & 63) == 0) { red[wave] = s1; red[4 + wave] = s2; }
  __syncthreads();
  s1 = red[0] + red[1] + red[2] + red[3];
  s2 = red[4] + red[5] + red[6] + red[7];
  float mu = s1 * (1.f / C_);
  float rs = rsqrtf(s2 * (1.f / C_) - mu * mu + 1e-5f);
  out[(size_t)row * C_ + c] = f2bf((v - mu) * rs * g[c] + bta[c]);
}

// ---------------------------------------------------------------------------
// ln_dual: out1 = LN(x+pe)*g1+b1, out2 = LN(x)*g2+b2. One read of x.
// ---------------------------------------------------------------------------
__global__ __launch_bounds__(256) void ln_dual(
    const float* __restrict__ x, const float* __restrict__ pe,
    const float* __restrict__ g1, const float* __restrict__ b1a,
    const float* __restrict__ g2, const float* __restrict__ b2a,
    unsigned short* __restrict__ out1, unsigned short* __restrict__ out2) {
  int row = blockIdx.x, c = threadIdx.x;
  float v = x[(size_t)row * C_ + c];
  float vp = v + pe[(size_t)(row % 88) * C_ + c];
  float s1 = v, s2 = v * v, t1 = vp, t2 = vp * vp;
#pragma unroll
  for (int m = 32; m > 0; m >>= 1) {
    s1 += __shfl_xor(s1, m, 64); s2 += __shfl_xor(s2, m, 64);
    t1 += __shfl_xor(t1, m, 64); t2 += __shfl_xor(t2, m, 64);
  }
  __shared__ float red[16];
  int wave = c >> 6;
  if ((c & 63) == 0) {
    red[wave] = s1; red[4 + wave] = s2; red[8 + wave] = t1; red[12 + wave] = t2;
  }
  __syncthreads();
  s1 = red[0] + red[1] + red[2] + red[3];
  s2 = red[4] + red[5] + red[6] + red[7];
  t1 = red[8] + red[9] + red[10] + red[11];
  t2 = red[12] + red[13] + red[14] + red[15];
  float mu = s1 * (1.f / C_), rs = rsqrtf(s2 * (1.f / C_) - mu * mu + 1e-5f);
  float mup = t1 * (1.f / C_), rsp = rsqrtf(t2 * (1.f / C_) - mup * mup + 1e-5f);
  out1[(size_t)row * C_ + c] = f2bf((vp - mup) * rsp * g1[c] + b1a[c]);
  out2[(size_t)row * C_ + c] = f2bf((v - mu) * rs * g2[c] + b2a[c]);
}

// ---------------------------------------------------------------------------
// GEMM: out[M,N] = A[M,K](bf16) @ Bt[N,K](bf16)^T, fp32 acc.
// Register double-buffer: next K-tile loads overlap current MFMA phase.
// ---------------------------------------------------------------------------
__global__ __launch_bounds__(256) void gemm_bt(
    const unsigned short* __restrict__ A, const unsigned short* __restrict__ Bt,
    int M, int N, int K,
    const float* __restrict__ bias, const float* __restrict__ resid,
    float* __restrict__ outF, unsigned short* __restrict__ outB, int act_gelu) {
  __shared__ __attribute__((aligned(16))) unsigned short As[64][32];
  __shared__ __attribute__((aligned(16))) unsigned short Bs[64][32];
  const int tiles_n = N >> 6;
  const int bm = blockIdx.x / tiles_n;
  const int bn = blockIdx.x % tiles_n;
  const int tid = threadIdx.x;
  const int wave = tid >> 6, lane = tid & 63;
  const int quad = lane >> 4, lr = lane & 15;
  const int wm = (wave >> 1) << 5, wn = (wave & 1) << 5;
  const int lrow = tid >> 2;
  const int lcol = (tid & 3) << 3;
  const size_t a_base = (size_t)(bm * 64 + lrow) * K + lcol;
  const size_t b_base = (size_t)(bn * 64 + lrow) * K + lcol;
  f32x4 acc[2][2] = {};
  uint4 areg = *(const uint4*)(A + a_base);
  uint4 breg = *(const uint4*)(Bt + b_base);
  for (int k0 = 0; k0 < K; k0 += 32) {
    *(uint4*)&As[lrow][lcol] = areg;
    *(uint4*)&Bs[lrow][lcol] = breg;
    __syncthreads();
    if (k0 + 32 < K) {
      areg = *(const uint4*)(A + a_base + k0 + 32);
      breg = *(const uint4*)(Bt + b_base + k0 + 32);
    }
    bf16x8 af0 = *(const bf16x8*)&As[wm + lr][quad << 3];
    bf16x8 af1 = *(const bf16x8*)&As[wm + 16 + lr][quad << 3];
    bf16x8 bf0 = *(const bf16x8*)&Bs[wn + lr][quad << 3];
    bf16x8 bf1 = *(const bf16x8*)&Bs[wn + 16 + lr][quad << 3];
    acc[0][0] = __builtin_amdgcn_mfma_f32_16x16x32_bf16(af0, bf0, acc[0][0], 0, 0, 0);
    acc[0][1] = __builtin_amdgcn_mfma_f32_16x16x32_bf16(af0, bf1, acc[0][1], 0, 0, 0);
    acc[1][0] = __builtin_amdgcn_mfma_f32_16x16x32_bf16(af1, bf0, acc[1][0], 0, 0, 0);
    acc[1][1] = __builtin_amdgcn_mfma_f32_16x16x32_bf16(af1, bf1, acc[1][1], 0, 0, 0);
    __syncthreads();
  }
#pragma unroll
  for (int i = 0; i < 2; i++)
#pragma unroll
    for (int j = 0; j < 2; j++)
#pragma unroll
      for (int rr = 0; rr < 4; rr++) {
        int row = bm * 64 + wm + i * 16 + quad * 4 + rr;
        int col = bn * 64 + wn + j * 16 + lr;
        float val = acc[i][j][rr];
        if (bias) val += bias[col];
        if (act_gelu) val = 0.5f * val * (1.f + erff(val * 0.70710678118654752f));
        if (resid) val += resid[(size_t)row * N + col];
        if (outF) outF[(size_t)row * N + col] = val;
        else outB[(size_t)row * N + col] = f2bf(val);
      }
}

// ---------------------------------------------------------------------------
// gemm_bt_st: like gemm_bt but writes f32 with row stride ldc (+bias).
// ---------------------------------------------------------------------------
__global__ __launch_bounds__(256) void gemm_bt_st(
    const unsigned short* __restrict__ A, const unsigned short* __restrict__ Bt,
    int M, int N, int K, int ldc,
    const float* __restrict__ bias, float* __restrict__ outF) {
  __shared__ __attribute__((aligned(16))) unsigned short As[64][32];
  __shared__ __attribute__((aligned(16))) unsigned short Bs[64][32];
  const int tiles_n = N >> 6;
  const int bm = blockIdx.x / tiles_n;
  const int bn = blockIdx.x % tiles_n;
  const int tid = threadIdx.x;
  const int wave = tid >> 6, lane = tid & 63;
  const int quad = lane >> 4, lr = lane & 15;
  const int wm = (wave >> 1) << 5, wn = (wave & 1) << 5;
  const int lrow = tid >> 2;
  const int lcol = (tid & 3) << 3;
  const size_t a_base = (size_t)(bm * 64 + lrow) * K + lcol;
  const size_t b_base = (size_t)(bn * 64 + lrow) * K + lcol;
  f32x4 acc[2][2] = {};
  uint4 areg = *(const uint4*)(A + a_base);
  uint4 breg = *(const uint4*)(Bt + b_base);
  for (int k0 = 0; k0 < K; k0 += 32) {
    *(uint4*)&As[lrow][lcol] = areg;
    *(uint4*)&Bs[lrow][lcol] = breg;
    __syncthreads();
    if (k0 + 32 < K) {
      areg = *(const uint4*)(A + a_base + k0 + 32);
      breg = *(const uint4*)(Bt + b_base + k0 + 32);
    }
    bf16x8 af0 = *(const bf16x8*)&As[wm + lr][quad << 3];
    bf16x8 af1 = *(const bf16x8*)&As[wm + 16 + lr][quad << 3];
    bf16x8 bf0 = *(const bf16x8*)&Bs[wn + lr][quad << 3];
    bf16x8 bf1 = *(const bf16x8*)&Bs[wn + 16 + lr][quad << 3];
    acc[0][0] = __builtin_amdgcn_mfma_f32_16x16x32_bf16(af0, bf0, acc[0][0], 0, 0, 0);
    acc[0][1] = __builtin_amdgcn_mfma_f32_16x16x32_bf16(af0, bf1, acc[0][1], 0, 0, 0);
    acc[1][0] = __builtin_amdgcn_mfma_f32_16x16x32_bf16(af1, bf0, acc[1][0], 0, 0, 0);
    acc[1][1] = __builtin_amdgcn_mfma_f32_16x16x32_bf16(af1, bf1, acc[1][1], 0, 0, 0);
    __syncthreads();
  }
#pragma unroll
  for (int i = 0; i < 2; i++)
#pragma unroll
    for (int j = 0; j < 2; j++)
#pragma unroll
      for (int rr = 0; rr < 4; rr++) {
        int row = bm * 64 + wm + i * 16 + quad * 4 + rr;
        int col = bn * 64 + wn + j * 16 + lr;
        outF[(size_t)row * ldc + col] = acc[i][j][rr] + bias[col];
      }
}

// ---------------------------------------------------------------------------
// cross_attn2: per (b,w). qt [BW_,2048] bf16; kn/vn [BWH_,256] bf16.
// ---------------------------------------------------------------------------
#define KSTR 264
__global__ __launch_bounds__(256) void cross_attn2(
    const unsigned short* __restrict__ qt_g,
    const unsigned short* __restrict__ kn, const unsigned short* __restrict__ vn,
    unsigned short* __restrict__ ctx_g) {
  int bw = blockIdx.x;
  int tid = threadIdx.x;
  __shared__ __attribute__((aligned(16))) unsigned short qtl[8][KSTR];
  __shared__ __attribute__((aligned(16))) unsigned short knl[32][KSTR];
  __shared__ __attribute__((aligned(16))) unsigned short vnl[32][KSTR];
  __shared__ float s_sc[32 * 9];
  __shared__ float ps[8 * 36];
  __shared__ __attribute__((aligned(16))) unsigned short ctxl[2048];
  {
    uint4 qv = *(const uint4*)(qt_g + (size_t)bw * 2048 + tid * 8);
    int h = tid >> 5, c0 = (tid & 31) * 8;
    *(uint4*)&qtl[h][c0] = qv;
    int j = tid >> 3, cs = (tid & 7) * 32;
    const unsigned short* kr = kn + ((size_t)bw * 32 + j) * 256 + cs;
    const unsigned short* vr = vn + ((size_t)bw * 32 + j) * 256 + cs;
#pragma unroll
    for (int k = 0; k < 4; k++) {
      *(uint4*)&knl[j][cs + k * 8] = *(const uint4*)(kr + k * 8);
      *(uint4*)&vnl[j][cs + k * 8] = *(const uint4*)(vr + k * 8);
    }
  }
  __syncthreads();
  {
    int j = tid >> 3, h = tid & 7;
    float acc = 0.f;
#pragma unroll
    for (int c8 = 0; c8 < 32; c8++) {
      bf16x8 kk = *(const bf16x8*)&knl[j][c8 * 8];
      bf16x8 qq = *(const bf16x8*)&qtl[h][c8 * 8];
#pragma unroll
      for (int i = 0; i < 8; i++) acc += (float)qq[i] * (float)kk[i];
    }
    s_sc[j * 9 + h] = acc;
  }
  __syncthreads();
  {
    int h = tid >> 5, j = tid & 31;
    float s = s_sc[j * 9 + h];
    float mx = s;
#pragma unroll
    for (int m = 16; m > 0; m >>= 1) mx = fmaxf(mx, __shfl_xor(mx, m, 32));
    float e = __expf(s - mx);
    float sum = e;
#pragma unroll
    for (int m = 16; m > 0; m >>= 1) sum += __shfl_xor(sum, m, 32);
    ps[h * 36 + j] = e / sum;
  }
  __syncthreads();
  {
    int h = tid & 7, c0 = (tid >> 3) * 8;
    float acc[8];
#pragma unroll
    for (int i = 0; i < 8; i++) acc[i] = 0.f;
#pragma unroll 8
    for (int j = 0; j < 32; j++) {
      float p = ps[h * 36 + j];
      bf16x8 vv = *(const bf16x8*)&vnl[j][c0];
#pragma unroll
      for (int i = 0; i < 8; i++) acc[i] += p * (float)vv[i];
    }
    unsigned short pk[8];
#pragma unroll
    for (int i = 0; i < 8; i++) pk[i] = f2bf(acc[i]);
    *(uint4*)&ctxl[h * 256 + c0] = *(uint4*)pk;
  }
  __syncthreads();
  *(uint4*)(ctx_g + (size_t)bw * 2048 + tid * 8) = *(const uint4*)&ctxl[tid * 8];
}

// ---------------------------------------------------------------------------
// self_attn3: block=(b,h), 192 threads: pair (r=t>>1, dh=t&1) per query row.
// qkv f32 [BW_,768] (q+0,k+256,v+512). Scores in registers (44/lane).
// ---------------------------------------------------------------------------
__global__ __launch_bounds__(192) void self_attn3(
    const float* __restrict__ qkv, unsigned short* __restrict__ out) {
  int b = blockIdx.x >> 3;
  int h = blockIdx.x & 7;
  int t = threadIdx.x;
  __shared__ float kl[88][33];
  __shared__ float vl[88][33];
  for (int i = t; i < 704; i += 192) {
    int m = i >> 3, d4 = (i & 7) << 2;
    float4 kv4 = *(const float4*)(qkv + (size_t)(b * 88 + m) * 768 + 256 + h * 32 + d4);
    float4 vv4 = *(const float4*)(qkv + (size_t)(b * 88 + m) * 768 + 512 + h * 32 + d4);
    kl[m][d4 + 0] = kv4.x; kl[m][d4 + 1] = kv4.y; kl[m][d4 + 2] = kv4.z; kl[m][d4 + 3] = kv4.w;
    vl[m][d4 + 0] = vv4.x; vl[m][d4 + 1] = vv4.y; vl[m][d4 + 2] = vv4.z; vl[m][d4 + 3] = vv4.w;
  }
  __syncthreads();
  int r = t >> 1, dh = t & 1;
  if (r < 88) {
    const float* qrow = qkv + (size_t)(b * 88 + r) * 768 + h * 32;
    float qr[32];
#pragma unroll
    for (int g = 0; g < 8; g++) {
      float4 q4 = *(const float4*)(qrow + g * 4);
      qr[g * 4 + 0] = q4.x; qr[g * 4 + 1] = q4.y; qr[g * 4 + 2] = q4.z; qr[g * 4 + 3] = q4.w;
    }
    float sreg[44];
    float mx = -1e30f;
    int m0 = dh * 44;
    for (int mi = 0; mi < 44; mi++) {
      const float* krow = kl[m0 + mi];
      float s = 0.f;
#pragma unroll
      for (int d = 0; d < 32; d++) s += qr[d] * krow[d];
      s *= 0.17677669529663689f;
      sreg[mi] = s;
      mx = fmaxf(mx, s);
    }
    mx = fmaxf(mx, __shfl_xor(mx, 1, 64));
    float sum = 0.f;
    for (int mi = 0; mi < 44; mi++) { float e = __expf(sreg[mi] - mx); sreg[mi] = e; sum += e; }
    sum += __shfl_xor(sum, 1, 64);
    float inv = 1.f / sum;
    float o[32];
#pragma unroll
    for (int d = 0; d < 32; d++) o[d] = 0.f;
    for (int mi = 0; mi < 44; mi++) {
      float p = sreg[mi] * inv;
      const float* vrow = vl[m0 + mi];
#pragma unroll
      for (int d = 0; d < 32; d++) o[d] += p * vrow[d];
    }
#pragma unroll
    for (int d = 0; d < 32; d++) o[d] += __shfl_xor(o[d], 1, 64);
    unsigned short* orow = out + (size_t)(b * 88 + r) * 256 + h * 32 + dh * 16;
    uint4 u0, u1;
    int d0 = dh * 16;
    u0.x = pack2(o[d0 + 0], o[d0 + 1]);  u0.y = pack2(o[d0 + 2], o[d0 + 3]);
    u0.z = pack2(o[d0 + 4], o[d0 + 5]);  u0.w = pack2(o[d0 + 6], o[d0 + 7]);
    u1.x = pack2(o[d0 + 8], o[d0 + 9]);  u1.y = pack2(o[d0 + 10], o[d0 + 11]);
    u1.z = pack2(o[d0 + 12], o[d0 + 13]); u1.w = pack2(o[d0 + 14], o[d0 + 15]);
    *(uint4*)(orow) = u0;
    *(uint4*)(orow + 8) = u1;
  }
}

// ---------------------------------------------------------------------------
extern "C" void kernel_launch(void* const* d_in, const int* in_sizes, int n_in,
                              void* d_out, int out_size, void* d_ws, size_t ws_size,
                              hipStream_t stream) {
  (void)in_sizes; (void)n_in; (void)out_size; (void)ws_size;
  const float* pooled   = (const float*)d_in[0];
  const float* features = (const float*)d_in[1];
  const float* self_pe  = (const float*)d_in[2];
  const float* cross_pe = (const float*)d_in[3];
  const float* ln_qs_g = (const float*)d_in[4],  *ln_qs_b = (const float*)d_in[5];
  const float* ln_vs_g = (const float*)d_in[6],  *ln_vs_b = (const float*)d_in[7];
  const float* ln_qc_g = (const float*)d_in[8],  *ln_qc_b = (const float*)d_in[9];
  const float* ln_kv_g = (const float*)d_in[10], *ln_kv_b = (const float*)d_in[11];
  const float* ln_vc_g = (const float*)d_in[12], *ln_vc_b = (const float*)d_in[13];
  const float* ln_ffn_g = (const float*)d_in[14], *ln_ffn_b = (const float*)d_in[15];
  const float* Wq_s = (const float*)d_in[16], *Wk_s = (const float*)d_in[17];
  const float* Wv_s = (const float*)d_in[18], *Wp_s = (const float*)d_in[19];
  const float* Wq_c = (const float*)d_in[20], *Wk_c = (const float*)d_in[21];
  const float* Wv_c = (const float*)d_in[22], *Wp_c = (const float*)d_in[23];
  const float* bq_s = (const float*)d_in[24], *bv_s = (const float*)d_in[25];
  const float* bp_s = (const float*)d_in[26], *bq_c = (const float*)d_in[27];
  const float* bv_c = (const float*)d_in[28], *bp_c = (const float*)d_in[29];
  const float* W1 = (const float*)d_in[30], *b1 = (const float*)d_in[31];
  const float* W2 = (const float*)d_in[32], *b2 = (const float*)d_in[33];
  float* outp = (float*)d_out;
  char* ws = (char*)d_ws;

  // ---- workspace layout ----
  size_t off = 0;
  auto alloc = [&](size_t bytes) { size_t o = off; off = (off + bytes + 255) & ~(size_t)255; return o; };
  const size_t big = (size_t)BWH_ * C_ * 2;          // 69.2 MB each
  size_t KN  = alloc(big);
  size_t VN  = alloc(big);
  size_t QT  = alloc((size_t)BW_ * 2048 * 2);
  size_t CTX = alloc((size_t)BW_ * 2048 * 2);
  size_t MQK = alloc((size_t)2048 * 256 * 2);
  size_t MVP = alloc((size_t)256 * 2048 * 2);
  size_t BQK = alloc(2048 * 4);
  size_t BVP = alloc(256 * 4);
  size_t WQKVS = alloc((size_t)768 * 256 * 2);
  size_t BQKVS = alloc(768 * 4);
  size_t WPS = alloc(65536 * 2);
  size_t W1T = alloc(262144 * 2), W2T = alloc(262144 * 2);
  size_t QN_C = alloc((size_t)BW_ * C_ * 2);
  // phase-B overlays KN region (dead after cross_attn2)
  size_t offp = KN;
  auto allocP = [&](size_t bytes) { size_t o = offp; offp = (offp + bytes + 255) & ~(size_t)255; return o; };
  size_t X1    = allocP((size_t)BW_ * C_ * 4);
  size_t QN_S  = allocP((size_t)BW_ * C_ * 2);
  size_t VN_S  = allocP((size_t)BW_ * C_ * 2);
  size_t QKV_S = allocP((size_t)BW_ * 768 * 4);
  size_t S_O   = allocP((size_t)BW_ * C_ * 2);
  size_t X2    = allocP((size_t)BW_ * C_ * 4);
  size_t FFN   = allocP((size_t)BW_ * C_ * 2);
  size_t H1    = allocP((size_t)BW_ * F_ * 2);

  unsigned short* kn   = (unsigned short*)(ws + KN);
  unsigned short* vn   = (unsigned short*)(ws + VN);
  unsigned short* qt   = (unsigned short*)(ws + QT);
  unsigned short* ctx  = (unsigned short*)(ws + CTX);
  unsigned short* mqk  = (unsigned short*)(ws + MQK);
  unsigned short* mvp  = (unsigned short*)(ws + MVP);
  float* bqk = (float*)(ws + BQK);
  float* bvp = (float*)(ws + BVP);
  unsigned short* wqkvs = (unsigned short*)(ws + WQKVS);
  float* bqkvs = (float*)(ws + BQKVS);
  unsigned short* wps = (unsigned short*)(ws + WPS);
  unsigned short* w1t = (unsigned short*)(ws + W1T), *w2t = (unsigned short*)(ws + W2T);
  unsigned short* qn_c = (unsigned short*)(ws + QN_C);
  float*          x1   = (float*)(ws + X1);
  unsigned short* qn_s = (unsigned short*)(ws + QN_S);
  unsigned short* vn_s = (unsigned short*)(ws + VN_S);
  float* qkv_s = (float*)(ws + QKV_S);
  unsigned short* s_o  = (unsigned short*)(ws + S_O);
  float*          x2   = (float*)(ws + X2);
  unsigned short* ffn_n = (unsigned short*)(ws + FFN);
  unsigned short* h1    = (unsigned short*)(ws + H1);

  // 1. all prep (weights, folded matrices, LN(pooled)) in one launch
  prep_all<<<6017, 256, 0, stream>>>(
      Wq_s, Wk_s, Wv_s, Wp_s, W1, W2, Wq_c, Wk_c, Wv_c, Wp_c,
      bq_s, bv_s, bq_c, bv_c, bp_c, pooled, ln_qc_g, ln_qc_b,
      wqkvs, wps, w1t, w2t, mqk, mvp, bqk, bvp, bqkvs, qn_c);

  // 2. features -> kn, vn
  ln_transpose4<<<B_ * 176, 256, 0, stream>>>(features, cross_pe,
      ln_kv_g, ln_kv_b, ln_vc_g, ln_vc_b, kn, vn);

  // 3. q~ = qn_c @ Mqk^T + bqk
  gemm_bt<<<(BW_ / 64) * (2048 / 64), 256, 0, stream>>>(qn_c, mqk, BW_, 2048, 256,
      bqk, nullptr, nullptr, qt, 0);

  // 4. cross attention core
  cross_attn2<<<BW_, 256, 0, stream>>>(qt, kn, vn, ctx);

  // 5. x1 = ctx @ Mvp^T + bvp + pooled
  gemm_bt<<<(BW_ / 64) * (C_ / 64), 256, 0, stream>>>(ctx, mvp, BW_, C_, 2048,
      bvp, pooled, x1, nullptr, 0);

  // 6. qn_s = LN(x1+self_pe), vn_s = LN(x1)
  ln_dual<<<BW_, 256, 0, stream>>>(x1, self_pe, ln_qs_g, ln_qs_b,
                                   ln_vs_g, ln_vs_b, qn_s, vn_s);

  // 7. q|k from qn_s -> qkv_s cols [0,512); v from vn_s -> cols [512,768). ldc=768.
  gemm_bt_st<<<(BW_ / 64) * (512 / 64), 256, 0, stream>>>(qn_s, wqkvs, BW_, 512, 256,
      768, bqkvs, qkv_s);
  gemm_bt_st<<<(BW_ / 64) * (256 / 64), 256, 0, stream>>>(vn_s, wqkvs + 131072, BW_, 256, 256,
      768, bqkvs + 512, qkv_s + 512);

  // 8. self attention core
  self_attn3<<<B_ * 8, 192, 0, stream>>>(qkv_s, s_o);

  // 9. x2 = s_o @ Wp_s + bp_s + x1
  gemm_bt<<<(BW_ / 64) * (C_ / 64), 256, 0, stream>>>(s_o, wps, BW_, C_, C_,
      bp_s, x1, x2, nullptr, 0);

  // 10. FFN
  ln_rows<<<BW_, 256, 0, stream>>>(x2, ln_ffn_g, ln_ffn_b, ffn_n);
  gemm_bt<<<(BW_ / 64) * (F_ / 64), 256, 0, stream>>>(ffn_n, w1t, BW_, F_, C_,
      b1, nullptr, nullptr, h1, 1);
  gemm_bt<<<(BW_ / 64) * (C_ / 64), 256, 0, stream>>>(h1, w2t, BW_, C_, F_,
      b2, x2, outp, nullptr, 0);
}